// Round 9
// baseline (2279.589 us; speedup 1.0000x reference)
//
#include <hip/hip_runtime.h>
#include <cstddef>

// ---------------- constants ----------------
// B=8, S=1024, T=256, E=256, H=512, Senc=256
// ws layout (float words)
constexpr int OXB0 = 0;                         // (8, 1026, 256) padded ch-last embed(src)
constexpr int OXB1 = OXB0 + 8 * 1026 * 256;     // (8, 514, 256) after conv1+pool
constexpr int OXB2 = OXB1 + 8 * 514 * 256;      // (8, 258, 512) after conv2+pool
constexpr int OENC = OXB2 + 8 * 258 * 512;      // (8, 256, 512) enc
constexpr int OWR1 = OENC + 8 * 256 * 512;      // 768x256   conv1 W^T
constexpr int OWR2 = OWR1 + 768 * 256;          // 768x512   conv2 W^T
constexpr int OWR3 = OWR2 + 768 * 512;          // 1536x512  conv3 W^T
constexpr int OWR0 = OWR3 + 1536 * 512;         // 256x2048  wih0^T
constexpr int OTGT = OWR0 + 256 * 2048;         // 2048x256  embed(tgt), row = t*8+b
constexpr int OXG0 = OTGT + 2048 * 256;         // 2048x2048 xg0 = emb@wih0^T + biases
constexpr int OH0S = OXG0 + 2048 * 2048;        // 257*4096  h0 sequence [t][b][512]
constexpr int OH1S = OH0S + 257 * 4096;         // 257*4096  h1 sequence (dec = t>=1)
constexpr int OCTX = OH1S + 257 * 4096;         // 8*512 ctx per batch
constexpr int OFLG = OCTX + 8 * 512;            // 96 ints: COMPACT flags
// flags[0..31]  : layer0 block j -> t+1 when step t fully published
// flags[32..95] : layer1 block j -> t+1
// Compact 4B words: poller lanes read consecutive words -> ONE coalesced
// transaction per poll iteration (v7 lesson: strided flags = 64+ line loads/iter).

__device__ __forceinline__ float sigmf(float x) { return 1.f / (1.f + expf(-x)); }
__device__ __forceinline__ float4 relu4(float4 v, const float4& bv) {
    v.x = fmaxf(v.x + bv.x, 0.f); v.y = fmaxf(v.y + bv.y, 0.f);
    v.z = fmaxf(v.z + bv.z, 0.f); v.w = fmaxf(v.w + bv.w, 0.f); return v;
}
__device__ __forceinline__ float4 max4(const float4& a, const float4& b) {
    float4 r; r.x = fmaxf(a.x, b.x); r.y = fmaxf(a.y, b.y);
    r.z = fmaxf(a.z, b.z); r.w = fmaxf(a.w, b.w); return r;
}
__device__ __forceinline__ void fma4(float4& acc, const float4& a, const float4& b) {
    acc.x = fmaf(a.x, b.x, acc.x); acc.y = fmaf(a.y, b.y, acc.y);
    acc.z = fmaf(a.z, b.z, acc.z); acc.w = fmaf(a.w, b.w, acc.w);
}
__device__ __forceinline__ float hsum4(const float4& a) { return a.x + a.y + a.z + a.w; }

__device__ __forceinline__ unsigned long long aload64(const float* p) {
    return __hip_atomic_load((const unsigned long long*)p, __ATOMIC_RELAXED,
                             __HIP_MEMORY_SCOPE_AGENT);
}
__device__ __forceinline__ void astore32(float* p, float v) {
    __hip_atomic_store((unsigned int*)p, __float_as_uint(v), __ATOMIC_RELAXED,
                       __HIP_MEMORY_SCOPE_AGENT);
}
__device__ __forceinline__ int aloadi(const int* p) {
    return __hip_atomic_load(p, __ATOMIC_RELAXED, __HIP_MEMORY_SCOPE_AGENT);
}
__device__ __forceinline__ void astorei(int* p, int v) {
    __hip_atomic_store(p, v, __ATOMIC_RELAXED, __HIP_MEMORY_SCOPE_AGENT);
}
__device__ __forceinline__ float2 unpack64(unsigned long long v) {
    float2 f;
    f.x = __uint_as_float((unsigned)v);
    f.y = __uint_as_float((unsigned)(v >> 32));
    return f;
}

// ---------------- LSTM per-half compute (verified mappings from v4.1) ----------------
// Layer0 half: MAC + 5-level tree (32 values <-> 32 lanes) + gates + owner store.
__device__ __forceinline__ void l0_half(const float2 (&W)[4][2][8],
                                        const unsigned long long (&hv)[4][8],
                                        float xgv, float& cst, int ks,
                                        float* outp) {
    float2 acc[4][2][4];
#pragma unroll
    for (int g = 0; g < 4; ++g)
#pragma unroll
        for (int e = 0; e < 2; ++e)
#pragma unroll
            for (int bi = 0; bi < 4; ++bi) acc[g][e][bi] = make_float2(0.f, 0.f);
#pragma unroll
    for (int q = 0; q < 8; ++q)
#pragma unroll
        for (int bi = 0; bi < 4; ++bi) {
            float2 h2 = unpack64(hv[bi][q]);
#pragma unroll
            for (int g = 0; g < 4; ++g)
#pragma unroll
                for (int e = 0; e < 2; ++e) {
                    acc[g][e][bi].x = fmaf(W[g][e][q].x, h2.x, acc[g][e][bi].x);
                    acc[g][e][bi].y = fmaf(W[g][e][q].y, h2.y, acc[g][e][bi].y);
                }
        }
    float s[32];
#pragma unroll
    for (int g = 0; g < 4; ++g)
#pragma unroll
        for (int e = 0; e < 2; ++e)
#pragma unroll
            for (int bi = 0; bi < 4; ++bi)
                s[g * 8 + e * 4 + bi] = acc[g][e][bi].x + acc[g][e][bi].y;
    // 5-level tree: lane-bit k <-> value-bit k; lane ks ends with value ks
#pragma unroll
    for (int i = 0; i < 16; ++i) {
        float t_ = (ks & 16) ? s[i] : s[i + 16];
        float k_ = (ks & 16) ? s[i + 16] : s[i];
        s[i] = k_ + __shfl_xor(t_, 16);
    }
#pragma unroll
    for (int i = 0; i < 8; ++i) {
        float t_ = (ks & 8) ? s[i] : s[i + 8];
        float k_ = (ks & 8) ? s[i + 8] : s[i];
        s[i] = k_ + __shfl_xor(t_, 8);
    }
#pragma unroll
    for (int i = 0; i < 4; ++i) {
        float t_ = (ks & 4) ? s[i] : s[i + 4];
        float k_ = (ks & 4) ? s[i + 4] : s[i];
        s[i] = k_ + __shfl_xor(t_, 4);
    }
#pragma unroll
    for (int i = 0; i < 2; ++i) {
        float t_ = (ks & 2) ? s[i] : s[i + 2];
        float k_ = (ks & 2) ? s[i + 2] : s[i];
        s[i] = k_ + __shfl_xor(t_, 2);
    }
    {
        float t_ = (ks & 1) ? s[0] : s[1];
        float k_ = (ks & 1) ? s[1] : s[0];
        s[0] = k_ + __shfl_xor(t_, 1);
    }
    float red = s[0] + xgv;               // gate value v = ks
    float fgv = __shfl_xor(red, 8);
    float ggv = __shfl_xor(red, 16);
    float ogv = __shfl_xor(red, 24);
    if (ks < 8) {
        cst = sigmf(fgv) * cst + sigmf(red) * tanhf(ggv);
        float hval = sigmf(ogv) * tanhf(cst);
        astore32(outp, hval);
    }
}

// Layer1 half: MAC + tree (32 values over 64 lanes, spare bit4) + gates + store.
__device__ __forceinline__ void l1_half(const float2 (&W)[4][2][8],
                                        const unsigned long long (&hv)[4][8],
                                        float biasv, float& cst, int ks,
                                        float* outp) {
    float2 acc[4][2][4];
#pragma unroll
    for (int g = 0; g < 4; ++g)
#pragma unroll
        for (int e = 0; e < 2; ++e)
#pragma unroll
            for (int bi = 0; bi < 4; ++bi) acc[g][e][bi] = make_float2(0.f, 0.f);
#pragma unroll
    for (int q = 0; q < 8; ++q)
#pragma unroll
        for (int bi = 0; bi < 4; ++bi) {
            float2 h2 = unpack64(hv[bi][q]);
#pragma unroll
            for (int g = 0; g < 4; ++g)
#pragma unroll
                for (int e = 0; e < 2; ++e) {
                    acc[g][e][bi].x = fmaf(W[g][e][q].x, h2.x, acc[g][e][bi].x);
                    acc[g][e][bi].y = fmaf(W[g][e][q].y, h2.y, acc[g][e][bi].y);
                }
        }
    float s[32];
#pragma unroll
    for (int g = 0; g < 4; ++g)
#pragma unroll
        for (int e = 0; e < 2; ++e)
#pragma unroll
            for (int bi = 0; bi < 4; ++bi)
                s[g * 8 + e * 4 + bi] = acc[g][e][bi].x + acc[g][e][bi].y;
    // lane bit5 <-> value bit4; bits 3..0 direct; lane bit4 spare
#pragma unroll
    for (int i = 0; i < 16; ++i) {
        float t_ = (ks & 32) ? s[i] : s[i + 16];
        float k_ = (ks & 32) ? s[i + 16] : s[i];
        s[i] = k_ + __shfl_xor(t_, 32);
    }
#pragma unroll
    for (int i = 0; i < 8; ++i) {
        float t_ = (ks & 8) ? s[i] : s[i + 8];
        float k_ = (ks & 8) ? s[i + 8] : s[i];
        s[i] = k_ + __shfl_xor(t_, 8);
    }
#pragma unroll
    for (int i = 0; i < 4; ++i) {
        float t_ = (ks & 4) ? s[i] : s[i + 4];
        float k_ = (ks & 4) ? s[i + 4] : s[i];
        s[i] = k_ + __shfl_xor(t_, 4);
    }
#pragma unroll
    for (int i = 0; i < 2; ++i) {
        float t_ = (ks & 2) ? s[i] : s[i + 2];
        float k_ = (ks & 2) ? s[i + 2] : s[i];
        s[i] = k_ + __shfl_xor(t_, 2);
    }
    {
        float t_ = (ks & 1) ? s[0] : s[1];
        float k_ = (ks & 1) ? s[1] : s[0];
        s[0] = k_ + __shfl_xor(t_, 1);
    }
    // spare bit: (l, l^16) hold half-sums of the same value
    s[0] += __shfl_xor(s[0], 16);
    float red = s[0] + biasv;
    float fgv = __shfl_xor(red, 8);       // flip v3
    float ggv = __shfl_xor(red, 32);      // flip v4
    float ogv = __shfl_xor(red, 40);      // flip v4,v3
    if (ks < 8) {
        cst = sigmf(fgv) * cst + sigmf(red) * tanhf(ggv);
        float hval = sigmf(ogv) * tanhf(cst);
        astore32(outp, hval);
    }
}

// ---------------- init ----------------
__global__ void init_kernel(float* __restrict__ ws, int* __restrict__ flags) {
    int idx = blockIdx.x * 256 + threadIdx.x;
    int stride = gridDim.x * 256;
    for (int i = idx; i < 4096; i += stride) {
        ws[OH0S + i] = 0.f;
        ws[OH1S + i] = 0.f;
    }
    for (int i = idx; i < 96; i += stride) flags[i] = 0;
    for (int i = idx; i < 8 * 2 * 256; i += stride) {
        int b = i >> 9, rr = (i >> 8) & 1, c = i & 255;
        ws[OXB1 + b * 131584 + (rr ? 513 : 0) * 256 + c] = 0.f;
    }
    for (int i = idx; i < 8 * 2 * 512; i += stride) {
        int b = i >> 10, rr = (i >> 9) & 1, c = i & 511;
        ws[OXB2 + b * 132096 + (rr ? 257 : 0) * 512 + c] = 0.f;
    }
}

// ---------------- embedding gathers ----------------
__global__ void embed_src_kernel(const int* __restrict__ src, const float* __restrict__ emb,
                                 float* __restrict__ xb0) {
    int fi = blockIdx.x * 256 + threadIdx.x;          // float4 index, total 8*1026*64
    int e4 = fi & 63;
    int r = fi >> 6;
    int b = r / 1026;
    int p = r - b * 1026;
    float4 v = make_float4(0.f, 0.f, 0.f, 0.f);
    if (p > 0 && p < 1025) {
        int row = src[b * 1024 + (p - 1)];
        v = *(const float4*)(emb + row * 256 + e4 * 4);
    }
    *(float4*)(xb0 + (size_t)fi * 4) = v;
}

__global__ void gather_tgt_kernel(const int* __restrict__ tgt, const float* __restrict__ emb,
                                  float* __restrict__ et) {
    int fi = blockIdx.x * 256 + threadIdx.x;          // total 2048*64
    int e4 = fi & 63;
    int r = fi >> 6;                                  // m = t*8 + b
    int t = r >> 3, b = r & 7;
    int row = tgt[b * 256 + t];
    *(float4*)(et + (size_t)fi * 4) = *(const float4*)(emb + row * 256 + e4 * 4);
}

// ---------------- weight transposes ----------------
__global__ void tr_conv_kernel(const float* __restrict__ w, float* __restrict__ wr,
                               int Cout, int Cin) {
    int idx = blockIdx.x * 256 + threadIdx.x;
    int co = idx / (Cin * 3);
    int rem = idx - co * Cin * 3;
    int ci = rem / 3;
    int dk = rem - ci * 3;
    wr[(dk * Cin + ci) * Cout + co] = w[idx];
}
__global__ void tr_mat_kernel(const float* __restrict__ w, float* __restrict__ wr,
                              int N, int K) {
    int idx = blockIdx.x * 256 + threadIdx.x;
    int n = idx / K;
    int k = idx - n * K;
    wr[k * N + n] = w[idx];
}

// ---------------- generic tiled GEMM (unchanged, passing) ----------------
__launch_bounds__(256)
__global__ void gemm_kernel(const float* __restrict__ A, int aBS, int RS, int K,
                            const float* __restrict__ Bw, int N,
                            const float* __restrict__ bias, const float* __restrict__ bias2,
                            float* __restrict__ out, int oBS, int mode) {
    __shared__ float As[32 * 68];
    __shared__ float Bs[32 * 64];
    const int tid = threadIdx.x;
    const int tl = tid & 15, tco = tid >> 4;
    const int m0 = blockIdx.x * 64, n0 = blockIdx.y * 64;
    const int b = blockIdx.z;
    const float* Ab = A + (size_t)b * aBS;
    float4 acc0 = make_float4(0, 0, 0, 0), acc1 = acc0, acc2 = acc0, acc3 = acc0;

    for (int k0 = 0; k0 < K; k0 += 32) {
#pragma unroll
        for (int p = 0; p < 2; ++p) {
            int f = p * 256 + tid;
            int row = f >> 3, j4 = f & 7;
            float4 av = *(const float4*)(Ab + (size_t)(m0 + row) * RS + k0 + j4 * 4);
            int kb = j4 * 4;
            As[(kb + 0) * 68 + row] = av.x;
            As[(kb + 1) * 68 + row] = av.y;
            As[(kb + 2) * 68 + row] = av.z;
            As[(kb + 3) * 68 + row] = av.w;
        }
#pragma unroll
        for (int p = 0; p < 2; ++p) {
            int f = p * 256 + tid;
            int kk = f >> 4, j4 = f & 15;
            *(float4*)(&Bs[kk * 64 + j4 * 4]) =
                *(const float4*)(Bw + (size_t)(k0 + kk) * N + n0 + j4 * 4);
        }
        __syncthreads();
#pragma unroll
        for (int kk = 0; kk < 32; ++kk) {
            float4 a4 = *(const float4*)(&As[kk * 68 + tl * 4]);
            float4 b4 = *(const float4*)(&Bs[kk * 64 + tco * 4]);
            acc0.x = fmaf(a4.x, b4.x, acc0.x); acc0.y = fmaf(a4.x, b4.y, acc0.y);
            acc0.z = fmaf(a4.x, b4.z, acc0.z); acc0.w = fmaf(a4.x, b4.w, acc0.w);
            acc1.x = fmaf(a4.y, b4.x, acc1.x); acc1.y = fmaf(a4.y, b4.y, acc1.y);
            acc1.z = fmaf(a4.y, b4.z, acc1.z); acc1.w = fmaf(a4.y, b4.w, acc1.w);
            acc2.x = fmaf(a4.z, b4.x, acc2.x); acc2.y = fmaf(a4.z, b4.y, acc2.y);
            acc2.z = fmaf(a4.z, b4.z, acc2.z); acc2.w = fmaf(a4.z, b4.w, acc2.w);
            acc3.x = fmaf(a4.w, b4.x, acc3.x); acc3.y = fmaf(a4.w, b4.y, acc3.y);
            acc3.z = fmaf(a4.w, b4.z, acc3.z); acc3.w = fmaf(a4.w, b4.w, acc3.w);
        }
        __syncthreads();
    }

    int nb = n0 + tco * 4;
    float4 bv;
    bv.x = bias[nb + 0]; bv.y = bias[nb + 1]; bv.z = bias[nb + 2]; bv.w = bias[nb + 3];
    if (bias2) { bv.x += bias2[nb + 0]; bv.y += bias2[nb + 1]; bv.z += bias2[nb + 2]; bv.w += bias2[nb + 3]; }

    if (mode == 0) {
        float4 v0 = acc0, v1 = acc1, v2 = acc2, v3 = acc3;
        v0.x += bv.x; v0.y += bv.y; v0.z += bv.z; v0.w += bv.w;
        v1.x += bv.x; v1.y += bv.y; v1.z += bv.z; v1.w += bv.w;
        v2.x += bv.x; v2.y += bv.y; v2.z += bv.z; v2.w += bv.w;
        v3.x += bv.x; v3.y += bv.y; v3.z += bv.z; v3.w += bv.w;
        int mr = m0 + tl * 4;
        *(float4*)(out + (size_t)(mr + 0) * N + nb) = v0;
        *(float4*)(out + (size_t)(mr + 1) * N + nb) = v1;
        *(float4*)(out + (size_t)(mr + 2) * N + nb) = v2;
        *(float4*)(out + (size_t)(mr + 3) * N + nb) = v3;
    } else if (mode == 1) {
        float4 v0 = relu4(acc0, bv), v1 = relu4(acc1, bv), v2 = relu4(acc2, bv), v3 = relu4(acc3, bv);
        float4 p0 = max4(v0, v1), p1 = max4(v2, v3);
        int lout = (m0 + tl * 4) >> 1;
        float* ob = out + (size_t)b * oBS + (size_t)(1 + lout) * N + nb;
        *(float4*)ob = p0;
        *(float4*)(ob + N) = p1;
    } else {
        float4 v0 = relu4(acc0, bv), v1 = relu4(acc1, bv), v2 = relu4(acc2, bv), v3 = relu4(acc3, bv);
        int mr = m0 + tl * 4;
        float* ob = out + (size_t)b * oBS + (size_t)mr * N + nb;
        *(float4*)(ob + 0 * N) = v0;
        *(float4*)(ob + 1 * N) = v1;
        *(float4*)(ob + 2 * N) = v2;
        *(float4*)(ob + 3 * N) = v3;
    }
}

// ---------------- persistent 2-layer LSTM (v8: v4.1 protocol + compact flags + 96 blocks) ----------------
// 96 blocks x 256 threads. Blocks 0..31: layer0, 16 units each as two sequential
// 8-unit halves (e0 = wg0*2 + u2) reusing the verified v4.1 mappings. Blocks
// 32..95: layer1, 8 units each as two 4-unit halves (e1 = wg1*2 + u2).
// Protocol = v4.1 (best, 1177us): single-wave parallel flag poll + barrier
// broadcast + block flag. Changes: compact 4B flags (1 coalesced transaction per
// poll iter vs 64 line loads), halved producer/consumer fan (straggler tail,
// fabric load), and ALL waves drain vmcnt before the publish barrier (v4.1 only
// drained wave0 - latent race).
__launch_bounds__(256, 1)
__global__ void lstm_kernel(const float* __restrict__ xg0,
                            const float* __restrict__ whh0,
                            const float* __restrict__ wih1,
                            const float* __restrict__ whh1,
                            const float* __restrict__ bih1,
                            const float* __restrict__ bhh1,
                            float* __restrict__ h0s, float* __restrict__ h1s,
                            int* __restrict__ flags) {
    const int tid = threadIdx.x;
    const int wg = blockIdx.x;

    if (wg < 32) {
        // ----- layer 0: units wg0*16 .. +16 as halves A (e0A) and B (e0B) -----
        const int wg0 = wg;
        const int cg = tid >> 6;
        const int bg = (tid >> 5) & 1;
        const int ks = tid & 31;
        const int e0A = wg0 * 2, e0B = wg0 * 2 + 1;
        float2 WA[4][2][8], WB[4][2][8];
#pragma unroll
        for (int g = 0; g < 4; ++g)
#pragma unroll
            for (int e = 0; e < 2; ++e) {
                const float* wrA = whh0 + (size_t)(g * 512 + e0A * 8 + cg * 2 + e) * 512 + ks * 2;
                const float* wrB = whh0 + (size_t)(g * 512 + e0B * 8 + cg * 2 + e) * 512 + ks * 2;
#pragma unroll
                for (int q = 0; q < 8; ++q) {
                    WA[g][e][q] = *(const float2*)(wrA + q * 64);
                    WB[g][e][q] = *(const float2*)(wrB + q * 64);
                }
            }
        const int vg = ks >> 3, ve = (ks >> 2) & 1, vbi = ks & 3;
        const int vb = bg * 4 + vbi;
        const size_t xgoffA = (size_t)vb * 2048 + vg * 512 + e0A * 8 + cg * 2 + ve;
        const size_t xgoffB = (size_t)vb * 2048 + vg * 512 + e0B * 8 + cg * 2 + ve;
        const int ob = bg * 4 + (ks & 3);
        const int ou = cg * 2 + ((ks >> 2) & 1);
        const size_t obaseA = (size_t)ob * 512 + e0A * 8 + ou;
        const size_t obaseB = (size_t)ob * 512 + e0B * 8 + ou;
        float cstA = 0.f, cstB = 0.f;

        for (int t = 0; t < 256; ++t) {
            float xgvA = xg0[(size_t)t * 16384 + xgoffA];
            float xgvB = xg0[(size_t)t * 16384 + xgoffB];
            if (t > 0 && tid < 32) {
                int gd = 1 << 20;
                while (aloadi(&flags[tid]) < t && --gd) {}
            }
            __syncthreads();
            unsigned long long hv[4][8];
#pragma unroll
            for (int bi = 0; bi < 4; ++bi) {
                const float* hb = h0s + (size_t)t * 4096 + (bg * 4 + bi) * 512 + ks * 2;
#pragma unroll
                for (int q = 0; q < 8; ++q)
                    hv[bi][q] = aload64(hb + q * 64);
            }
            float* pl = h0s + (size_t)(t + 1) * 4096;
            l0_half(WA, hv, xgvA, cstA, ks, pl + obaseA);
            l0_half(WB, hv, xgvB, cstB, ks, pl + obaseB);
            asm volatile("s_waitcnt vmcnt(0)" ::: "memory");   // ALL waves drain
            __syncthreads();
            if (tid == 0) astorei(&flags[wg0], t + 1);
        }
    } else {
        // ----- layer 1: units wg1*8 .. +8 as halves (e1 = wg1*2 + u2) -----
        const int wg1 = wg - 32;
        const int w = tid >> 6;
        const int cg = w >> 1, bgv = w & 1;
        const int ks = tid & 63;
        const int e1A = wg1 * 2, e1B = wg1 * 2 + 1;
        float2 WA[4][2][8], WB[4][2][8];
#pragma unroll
        for (int g = 0; g < 4; ++g)
#pragma unroll
            for (int e = 0; e < 2; ++e) {
                const size_t roA = (size_t)(g * 512 + e1A * 4 + cg * 2 + e) * 512 + ks * 2;
                const size_t roB = (size_t)(g * 512 + e1B * 4 + cg * 2 + e) * 512 + ks * 2;
#pragma unroll
                for (int q = 0; q < 4; ++q) {
                    WA[g][e][q] = *(const float2*)(wih1 + roA + q * 128);
                    WB[g][e][q] = *(const float2*)(wih1 + roB + q * 128);
                }
#pragma unroll
                for (int q = 4; q < 8; ++q) {
                    WA[g][e][q] = *(const float2*)(whh1 + roA + (q - 4) * 128);
                    WB[g][e][q] = *(const float2*)(whh1 + roB + (q - 4) * 128);
                }
            }
        const int vg = (((ks >> 5) & 1) << 1) | ((ks >> 3) & 1);
        const int ve = (ks >> 2) & 1;
        const int rvA = vg * 512 + e1A * 4 + cg * 2 + ve;
        const int rvB = vg * 512 + e1B * 4 + cg * 2 + ve;
        const float biasA = bih1[rvA] + bhh1[rvA];
        const float biasB = bih1[rvB] + bhh1[rvB];
        const int ob = bgv * 4 + (ks & 3);
        const int ou = cg * 2 + ((ks >> 2) & 1);
        const size_t obaseA = (size_t)ob * 512 + e1A * 4 + ou;
        const size_t obaseB = (size_t)ob * 512 + e1B * 4 + ou;
        float cstA = 0.f, cstB = 0.f;

        for (int t = 0; t < 256; ++t) {
            // wave0 lanes<32: layer0 flags >= t+1; wave1 lanes 64..127: layer1 flags >= t
            if (tid < 32) {
                int gd = 1 << 20;
                while (aloadi(&flags[tid]) < t + 1 && --gd) {}
            } else if (tid >= 64 && tid < 128 && t > 0) {
                int gd = 1 << 20;
                while (aloadi(&flags[32 + tid - 64]) < t && --gd) {}
            }
            __syncthreads();
            unsigned long long hv[4][8];
#pragma unroll
            for (int bi = 0; bi < 4; ++bi) {
                const float* h0b = h0s + (size_t)(t + 1) * 4096 + (bgv * 4 + bi) * 512 + ks * 2;
                const float* h1b = h1s + (size_t)t * 4096 + (bgv * 4 + bi) * 512 + ks * 2;
#pragma unroll
                for (int q = 0; q < 4; ++q) hv[bi][q] = aload64(h0b + q * 128);
#pragma unroll
                for (int q = 4; q < 8; ++q) hv[bi][q] = aload64(h1b + (q - 4) * 128);
            }
            float* pl = h1s + (size_t)(t + 1) * 4096;
            l1_half(WA, hv, biasA, cstA, ks, pl + obaseA);
            l1_half(WB, hv, biasB, cstB, ks, pl + obaseB);
            asm volatile("s_waitcnt vmcnt(0)" ::: "memory");   // ALL waves drain
            __syncthreads();
            if (tid == 0) astorei(&flags[32 + wg1], t + 1);
        }
    }
}

// ---------------- attention (collapsed): ctx[b] = softmax(enc_p[b,:]) @ enc[b] ----------------
__launch_bounds__(256)
__global__ void attn_kernel(const float* __restrict__ enc, const float* __restrict__ attn_w,
                            float* __restrict__ ctx) {
    __shared__ float aw[512];
    __shared__ float pr[256];
    __shared__ float red[8];
    const int b = blockIdx.x, tid = threadIdx.x;
    if (tid < 128) ((float4*)aw)[tid] = ((const float4*)(attn_w + 512))[tid];
    __syncthreads();
    const float* er = enc + (size_t)(b * 256 + tid) * 512;
    float4 a4 = make_float4(0, 0, 0, 0);
#pragma unroll 8
    for (int i = 0; i < 128; ++i) {
        float4 e4 = *(const float4*)(er + i * 4);
        float4 w4 = *(const float4*)(aw + i * 4);
        fma4(a4, e4, w4);
    }
    float v = hsum4(a4);
    float m = v;
#pragma unroll
    for (int off = 32; off > 0; off >>= 1) m = fmaxf(m, __shfl_xor(m, off));
    if ((tid & 63) == 0) red[tid >> 6] = m;
    __syncthreads();
    if (tid == 0) red[4] = fmaxf(fmaxf(red[0], red[1]), fmaxf(red[2], red[3]));
    __syncthreads();
    float e = expf(v - red[4]);
    pr[tid] = e;
    float s = e;
#pragma unroll
    for (int off = 32; off > 0; off >>= 1) s += __shfl_xor(s, off);
    if ((tid & 63) == 0) red[tid >> 6] = s;
    __syncthreads();
    if (tid == 0) red[5] = red[0] + red[1] + red[2] + red[3];
    __syncthreads();
    float inv = 1.f / red[5];
    for (int hh = tid; hh < 512; hh += 256) {
        float acc = 0.f;
#pragma unroll 8
        for (int s2 = 0; s2 < 256; ++s2)
            acc = fmaf(pr[s2], enc[(size_t)(b * 256 + s2) * 512 + hh], acc);
        ctx[b * 512 + hh] = acc * inv;
    }
}

__global__ void bcast_ctx_kernel(const float* __restrict__ ctx, float* __restrict__ outc) {
    int fi = blockIdx.x * 256 + threadIdx.x;       // f4 idx, total 262144
    int h4 = fi & 127;
    int b = fi >> 15;
    ((float4*)outc)[fi] = ((const float4*)ctx)[b * 128 + h4];
}

// ---------------- output head: (b,t) row -> 10 logits ----------------
__launch_bounds__(256)
__global__ void out_proj_kernel(const float* __restrict__ h1s, const float* __restrict__ ow,
                                const float* __restrict__ ob, float* __restrict__ out) {
    int lane = threadIdx.x & 63;
    int m = blockIdx.x * 4 + (threadIdx.x >> 6);    // 0..2047, m = t*8+b
    int t = m >> 3, b = m & 7;
    const float* dr = h1s + (size_t)(t + 1) * 4096 + b * 512 + lane * 8;
    float4 d0 = *(const float4*)dr;
    float4 d1 = *(const float4*)(dr + 4);
    float acc[10];
#pragma unroll
    for (int v = 0; v < 10; ++v) {
        const float* wr = ow + v * 512 + lane * 8;
        float4 w0 = *(const float4*)wr, w1 = *(const float4*)(wr + 4);
        acc[v] = d0.x * w0.x + d0.y * w0.y + d0.z * w0.z + d0.w * w0.w +
                 d1.x * w1.x + d1.y * w1.y + d1.z * w1.z + d1.w * w1.w;
    }
#pragma unroll
    for (int v = 0; v < 10; ++v)
#pragma unroll
        for (int off = 32; off > 0; off >>= 1) acc[v] += __shfl_xor(acc[v], off);
    if (lane == 0) {
        float* o = out + (size_t)(b * 256 + t) * 10;
#pragma unroll
        for (int v = 0; v < 10; ++v) o[v] = acc[v] + ob[v];
    }
}

// ---------------- launch ----------------
extern "C" void kernel_launch(void* const* d_in, const int* in_sizes, int n_in,
                              void* d_out, int out_size, void* d_ws, size_t ws_size,
                              hipStream_t stream) {
    const int* src = (const int*)d_in[0];
    const int* tgt = (const int*)d_in[1];
    const float* emb = (const float*)d_in[2];
    const float* c1w = (const float*)d_in[3];
    const float* c1b = (const float*)d_in[4];
    const float* c2w = (const float*)d_in[5];
    const float* c2b = (const float*)d_in[6];
    const float* c3w = (const float*)d_in[7];
    const float* c3b = (const float*)d_in[8];
    const float* wih0 = (const float*)d_in[9];
    const float* whh0 = (const float*)d_in[10];
    const float* bih0 = (const float*)d_in[11];
    const float* bhh0 = (const float*)d_in[12];
    const float* wih1 = (const float*)d_in[13];
    const float* whh1 = (const float*)d_in[14];
    const float* bih1 = (const float*)d_in[15];
    const float* bhh1 = (const float*)d_in[16];
    const float* attn_w = (const float*)d_in[17];
    const float* out_w = (const float*)d_in[19];
    const float* out_b = (const float*)d_in[20];

    float* ws = (float*)d_ws;
    float* xb0 = ws + OXB0;
    float* xb1 = ws + OXB1;
    float* xb2 = ws + OXB2;
    float* enc = ws + OENC;
    float* wr1 = ws + OWR1;
    float* wr2 = ws + OWR2;
    float* wr3 = ws + OWR3;
    float* wr0 = ws + OWR0;
    float* etg = ws + OTGT;
    float* xg0 = ws + OXG0;
    float* h0s = ws + OH0S;
    float* h1s = ws + OH1S;
    float* ctx = ws + OCTX;
    int* flags = (int*)(ws + OFLG);
    float* outp = (float*)d_out;

    init_kernel<<<1024, 256, 0, stream>>>(ws, flags);
    embed_src_kernel<<<2052, 256, 0, stream>>>(src, emb, xb0);
    gather_tgt_kernel<<<512, 256, 0, stream>>>(tgt, emb, etg);
    tr_conv_kernel<<<768, 256, 0, stream>>>(c1w, wr1, 256, 256);
    tr_conv_kernel<<<1536, 256, 0, stream>>>(c2w, wr2, 512, 256);
    tr_conv_kernel<<<3072, 256, 0, stream>>>(c3w, wr3, 512, 512);
    tr_mat_kernel<<<2048, 256, 0, stream>>>(wih0, wr0, 2048, 256);

    // xg0 = embtgt @ wih0^T + bih0 + bhh0   (rows ordered t*8+b)
    gemm_kernel<<<dim3(32, 32, 1), 256, 0, stream>>>(etg, 0, 256, 256, wr0, 2048,
                                                     bih0, bhh0, xg0, 0, 0);
    // conv1 + relu + pool: (8,1026,256) -> (8,514,256)
    gemm_kernel<<<dim3(16, 4, 8), 256, 0, stream>>>(xb0, 262656, 256, 768, wr1, 256,
                                                    c1b, nullptr, xb1, 131584, 1);
    // conv2 + relu + pool: (8,514,256) -> (8,258,512)
    gemm_kernel<<<dim3(8, 8, 8), 256, 0, stream>>>(xb1, 131584, 256, 768, wr2, 512,
                                                   c2b, nullptr, xb2, 132096, 1);
    // conv3 + relu: (8,258,512) -> enc (8,256,512)
    gemm_kernel<<<dim3(4, 8, 8), 256, 0, stream>>>(xb2, 132096, 512, 1536, wr3, 512,
                                                   c3b, nullptr, enc, 131072, 2);
    // persistent 2-layer LSTM (compact flags, 96 blocks, two halves per block)
    lstm_kernel<<<96, 256, 0, stream>>>(xg0, whh0, wih1, whh1, bih1, bhh1,
                                        h0s, h1s, flags);
    // collapsed attention + context broadcast
    attn_kernel<<<8, 256, 0, stream>>>(enc, attn_w, ctx);
    bcast_ctx_kernel<<<1024, 256, 0, stream>>>(ctx, outp + 20480);
    // output logits
    out_proj_kernel<<<512, 256, 0, stream>>>(h1s, out_w, out_b, outp);
}

// Round 12
// 1414.271 us; speedup vs baseline: 1.6118x; 1.6118x over previous
//
#include <hip/hip_runtime.h>
#include <cstddef>

// ---------------- constants ----------------
// B=8, S=1024, T=256, E=256, H=512, Senc=256
// ws layout (float words)
constexpr int OXB0 = 0;                         // (8, 1026, 256) padded ch-last embed(src)
constexpr int OXB1 = OXB0 + 8 * 1026 * 256;     // (8, 514, 256) after conv1+pool
constexpr int OXB2 = OXB1 + 8 * 514 * 256;      // (8, 258, 512) after conv2+pool
constexpr int OENC = OXB2 + 8 * 258 * 512;      // (8, 256, 512) enc
constexpr int OWR1 = OENC + 8 * 256 * 512;      // 768x256   conv1 W^T
constexpr int OWR2 = OWR1 + 768 * 256;          // 768x512   conv2 W^T
constexpr int OWR3 = OWR2 + 768 * 512;          // 1536x512  conv3 W^T
constexpr int OWR0 = OWR3 + 1536 * 512;         // 256x2048  wih0^T
constexpr int OTGT = OWR0 + 256 * 2048;         // 2048x256  embed(tgt), row = t*8+b
constexpr int OXG0 = OTGT + 2048 * 256;         // 2048x2048 xg0 = emb@wih0^T + biases
constexpr int OH0S = OXG0 + 2048 * 2048;        // 257*4096  h0 sequence [t][b][512]
constexpr int OH1S = OH0S + 257 * 4096;         // 257*4096  h1 sequence (dec = t>=1)
constexpr int OCTX = OH1S + 257 * 4096;         // 8*512 ctx per batch
constexpr int OFLG = OCTX + 8 * 512;            // 192*16 ints: per-block flags

constexpr int FSTR = 16;                        // 64B flag stride (one line per producer)
// NaN sentinel: h = sigmoid*tanh can never be NaN. Planes t>=1 are pre-filled with
// it so consumers can VERIFY data after the (cheap) flag detect - this lets the
// producer signal without waiting for its store acks (no vmcnt drain in the loop).
constexpr unsigned SENT = 0x7FC0DEADu;

__device__ __forceinline__ float hsum4(const float4& a) { return a.x + a.y + a.z + a.w; }
__device__ __forceinline__ float4 relu4(float4 v, const float4& bv) {
    v.x = fmaxf(v.x + bv.x, 0.f); v.y = fmaxf(v.y + bv.y, 0.f);
    v.z = fmaxf(v.z + bv.z, 0.f); v.w = fmaxf(v.w + bv.w, 0.f); return v;
}
__device__ __forceinline__ float4 max4(const float4& a, const float4& b) {
    float4 r; r.x = fmaxf(a.x, b.x); r.y = fmaxf(a.y, b.y);
    r.z = fmaxf(a.z, b.z); r.w = fmaxf(a.w, b.w); return r;
}
__device__ __forceinline__ float sigmf(float x) { return 1.f / (1.f + expf(-x)); }
__device__ __forceinline__ void fma4(float4& acc, const float4& a, const float4& b) {
    acc.x = fmaf(a.x, b.x, acc.x); acc.y = fmaf(a.y, b.y, acc.y);
    acc.z = fmaf(a.z, b.z, acc.z); acc.w = fmaf(a.w, b.w, acc.w);
}

__device__ __forceinline__ unsigned long long aload64(const float* p) {
    return __hip_atomic_load((const unsigned long long*)p, __ATOMIC_RELAXED,
                             __HIP_MEMORY_SCOPE_AGENT);
}
__device__ __forceinline__ void astore32(float* p, float v) {
    __hip_atomic_store((unsigned int*)p, __float_as_uint(v), __ATOMIC_RELAXED,
                       __HIP_MEMORY_SCOPE_AGENT);
}
__device__ __forceinline__ int aloadi(const int* p) {
    return __hip_atomic_load(p, __ATOMIC_RELAXED, __HIP_MEMORY_SCOPE_AGENT);
}
__device__ __forceinline__ void astorei(int* p, int v) {
    __hip_atomic_store(p, v, __ATOMIC_RELAXED, __HIP_MEMORY_SCOPE_AGENT);
}
__device__ __forceinline__ float2 unpack64(unsigned long long v) {
    float2 f;
    f.x = __uint_as_float((unsigned)v);
    f.y = __uint_as_float((unsigned)(v >> 32));
    return f;
}
__device__ __forceinline__ unsigned sent_in(unsigned long long v) {
    return ((unsigned)v == SENT) | ((unsigned)(v >> 32) == SENT);
}

// ---------------- init: zero t=0 planes, sentinel t>=1 planes, flags, conv pads ----------------
__global__ void init_kernel(float* __restrict__ ws, int* __restrict__ flags) {
    int idx = blockIdx.x * 256 + threadIdx.x;
    int stride = gridDim.x * 256;
    float sentf = __uint_as_float(SENT);
    for (int i = idx; i < 257 * 4096; i += stride) {
        float v = (i < 4096) ? 0.f : sentf;
        ws[OH0S + i] = v;
        ws[OH1S + i] = v;
    }
    for (int i = idx; i < 192 * FSTR; i += stride) flags[i] = 0;
    for (int i = idx; i < 8 * 2 * 256; i += stride) {
        int b = i >> 9, rr = (i >> 8) & 1, c = i & 255;
        ws[OXB1 + b * 131584 + (rr ? 513 : 0) * 256 + c] = 0.f;
    }
    for (int i = idx; i < 8 * 2 * 512; i += stride) {
        int b = i >> 10, rr = (i >> 9) & 1, c = i & 511;
        ws[OXB2 + b * 132096 + (rr ? 257 : 0) * 512 + c] = 0.f;
    }
}

// ---------------- embedding gathers ----------------
__global__ void embed_src_kernel(const int* __restrict__ src, const float* __restrict__ emb,
                                 float* __restrict__ xb0) {
    int fi = blockIdx.x * 256 + threadIdx.x;          // float4 index, total 8*1026*64
    int e4 = fi & 63;
    int r = fi >> 6;                                  // 0 .. 8*1026-1
    int b = r / 1026;
    int p = r - b * 1026;
    float4 v = make_float4(0.f, 0.f, 0.f, 0.f);
    if (p > 0 && p < 1025) {
        int row = src[b * 1024 + (p - 1)];
        v = *(const float4*)(emb + row * 256 + e4 * 4);
    }
    *(float4*)(xb0 + (size_t)fi * 4) = v;
}

__global__ void gather_tgt_kernel(const int* __restrict__ tgt, const float* __restrict__ emb,
                                  float* __restrict__ et) {
    int fi = blockIdx.x * 256 + threadIdx.x;          // total 2048*64
    int e4 = fi & 63;
    int r = fi >> 6;                                  // m = t*8 + b
    int t = r >> 3, b = r & 7;
    int row = tgt[b * 256 + t];
    *(float4*)(et + (size_t)fi * 4) = *(const float4*)(emb + row * 256 + e4 * 4);
}

// ---------------- weight transposes ----------------
__global__ void tr_conv_kernel(const float* __restrict__ w, float* __restrict__ wr,
                               int Cout, int Cin) {
    int idx = blockIdx.x * 256 + threadIdx.x;
    int co = idx / (Cin * 3);
    int rem = idx - co * Cin * 3;
    int ci = rem / 3;
    int dk = rem - ci * 3;
    wr[(dk * Cin + ci) * Cout + co] = w[idx];
}
__global__ void tr_mat_kernel(const float* __restrict__ w, float* __restrict__ wr,
                              int N, int K) {
    int idx = blockIdx.x * 256 + threadIdx.x;
    int n = idx / K;
    int k = idx - n * K;
    wr[k * N + n] = w[idx];
}

// ---------------- generic tiled GEMM (unchanged, passing) ----------------
__launch_bounds__(256)
__global__ void gemm_kernel(const float* __restrict__ A, int aBS, int RS, int K,
                            const float* __restrict__ Bw, int N,
                            const float* __restrict__ bias, const float* __restrict__ bias2,
                            float* __restrict__ out, int oBS, int mode) {
    __shared__ float As[32 * 68];
    __shared__ float Bs[32 * 64];
    const int tid = threadIdx.x;
    const int tl = tid & 15, tco = tid >> 4;
    const int m0 = blockIdx.x * 64, n0 = blockIdx.y * 64;
    const int b = blockIdx.z;
    const float* Ab = A + (size_t)b * aBS;
    float4 acc0 = make_float4(0, 0, 0, 0), acc1 = acc0, acc2 = acc0, acc3 = acc0;

    for (int k0 = 0; k0 < K; k0 += 32) {
#pragma unroll
        for (int p = 0; p < 2; ++p) {
            int f = p * 256 + tid;
            int row = f >> 3, j4 = f & 7;
            float4 av = *(const float4*)(Ab + (size_t)(m0 + row) * RS + k0 + j4 * 4);
            int kb = j4 * 4;
            As[(kb + 0) * 68 + row] = av.x;
            As[(kb + 1) * 68 + row] = av.y;
            As[(kb + 2) * 68 + row] = av.z;
            As[(kb + 3) * 68 + row] = av.w;
        }
#pragma unroll
        for (int p = 0; p < 2; ++p) {
            int f = p * 256 + tid;
            int kk = f >> 4, j4 = f & 15;
            *(float4*)(&Bs[kk * 64 + j4 * 4]) =
                *(const float4*)(Bw + (size_t)(k0 + kk) * N + n0 + j4 * 4);
        }
        __syncthreads();
#pragma unroll
        for (int kk = 0; kk < 32; ++kk) {
            float4 a4 = *(const float4*)(&As[kk * 68 + tl * 4]);
            float4 b4 = *(const float4*)(&Bs[kk * 64 + tco * 4]);
            acc0.x = fmaf(a4.x, b4.x, acc0.x); acc0.y = fmaf(a4.x, b4.y, acc0.y);
            acc0.z = fmaf(a4.x, b4.z, acc0.z); acc0.w = fmaf(a4.x, b4.w, acc0.w);
            acc1.x = fmaf(a4.y, b4.x, acc1.x); acc1.y = fmaf(a4.y, b4.y, acc1.y);
            acc1.z = fmaf(a4.y, b4.z, acc1.z); acc1.w = fmaf(a4.y, b4.w, acc1.w);
            acc2.x = fmaf(a4.z, b4.x, acc2.x); acc2.y = fmaf(a4.z, b4.y, acc2.y);
            acc2.z = fmaf(a4.z, b4.z, acc2.z); acc2.w = fmaf(a4.z, b4.w, acc2.w);
            acc3.x = fmaf(a4.w, b4.x, acc3.x); acc3.y = fmaf(a4.w, b4.y, acc3.y);
            acc3.z = fmaf(a4.w, b4.z, acc3.z); acc3.w = fmaf(a4.w, b4.w, acc3.w);
        }
        __syncthreads();
    }

    int nb = n0 + tco * 4;
    float4 bv;
    bv.x = bias[nb + 0]; bv.y = bias[nb + 1]; bv.z = bias[nb + 2]; bv.w = bias[nb + 3];
    if (bias2) { bv.x += bias2[nb + 0]; bv.y += bias2[nb + 1]; bv.z += bias2[nb + 2]; bv.w += bias2[nb + 3]; }

    if (mode == 0) {
        float4 v0 = acc0, v1 = acc1, v2 = acc2, v3 = acc3;
        v0.x += bv.x; v0.y += bv.y; v0.z += bv.z; v0.w += bv.w;
        v1.x += bv.x; v1.y += bv.y; v1.z += bv.z; v1.w += bv.w;
        v2.x += bv.x; v2.y += bv.y; v2.z += bv.z; v2.w += bv.w;
        v3.x += bv.x; v3.y += bv.y; v3.z += bv.z; v3.w += bv.w;
        int mr = m0 + tl * 4;
        *(float4*)(out + (size_t)(mr + 0) * N + nb) = v0;
        *(float4*)(out + (size_t)(mr + 1) * N + nb) = v1;
        *(float4*)(out + (size_t)(mr + 2) * N + nb) = v2;
        *(float4*)(out + (size_t)(mr + 3) * N + nb) = v3;
    } else if (mode == 1) {
        float4 v0 = relu4(acc0, bv), v1 = relu4(acc1, bv), v2 = relu4(acc2, bv), v3 = relu4(acc3, bv);
        float4 p0 = max4(v0, v1), p1 = max4(v2, v3);
        int lout = (m0 + tl * 4) >> 1;
        float* ob = out + (size_t)b * oBS + (size_t)(1 + lout) * N + nb;
        *(float4*)ob = p0;
        *(float4*)(ob + N) = p1;
    } else {
        float4 v0 = relu4(acc0, bv), v1 = relu4(acc1, bv), v2 = relu4(acc2, bv), v3 = relu4(acc3, bv);
        int mr = m0 + tl * 4;
        float* ob = out + (size_t)b * oBS + (size_t)mr * N + nb;
        *(float4*)(ob + 0 * N) = v0;
        *(float4*)(ob + 1 * N) = v1;
        *(float4*)(ob + 2 * N) = v2;
        *(float4*)(ob + 3 * N) = v3;
    }
}

// ---------------- persistent 2-layer LSTM (v9: v4.1 + no-drain publish + sentinel verify) ----------------
// 192 blocks x 256 threads, 1 block/CU, W in VGPRs, zero LDS. Structure = v4.1
// (best measured: 1177us): per-block flags, single-wave parallel poll, barrier
// broadcast. v9 delta: producer signals WITHOUT waiting for store acks (the
// vmcnt(0) drain is deleted from the loop); ordering is enforced consumer-side
// by a sentinel verify on the h data (planes pre-filled with NaN pattern).
// Detection stays cheap (flags); the fat load is verified once, retried only in
// the rare flag-overtook-data window. Also fixes v4.1's wave0-only-drain race.
// (Rounds 10-11 were lost to infra failures on a dead container; this is an
// unchanged resubmit, attempt 3.)
__launch_bounds__(256, 1)
__global__ void lstm_kernel(const float* __restrict__ xg0,
                            const float* __restrict__ whh0,
                            const float* __restrict__ wih1,
                            const float* __restrict__ whh1,
                            const float* __restrict__ bih1,
                            const float* __restrict__ bhh1,
                            float* __restrict__ h0s, float* __restrict__ h1s,
                            int* __restrict__ flags) {
    const int tid = threadIdx.x;
    const int wg = blockIdx.x;

    if (wg < 64) {
        // ----- layer 0: 8 units (wg0*8 ..+7), K=512 -----
        const int wg0 = wg;
        const int cg = tid >> 6;          // wave: units cg*2+{0,1}
        const int bg = (tid >> 5) & 1;    // batch half
        const int ks = tid & 31;          // K-slice lane; k = q*64 + ks*2 + {0,1}
        float2 W2[4][2][8];
#pragma unroll
        for (int g = 0; g < 4; ++g)
#pragma unroll
            for (int e = 0; e < 2; ++e) {
                const float* wr = whh0 + (size_t)(g * 512 + wg0 * 8 + cg * 2 + e) * 512 + ks * 2;
#pragma unroll
                for (int q = 0; q < 8; ++q)
                    W2[g][e][q] = *(const float2*)(wr + q * 64);
            }
        // value mapping after tree: v = ks = (g<<3)|(e<<2)|bi
        const int vg = ks >> 3, ve = (ks >> 2) & 1, vbi = ks & 3;
        const int vb = bg * 4 + vbi;
        const size_t xgoff = (size_t)vb * 2048 + vg * 512 + wg0 * 8 + cg * 2 + ve;
        const int ob = bg * 4 + (ks & 3);
        const int ou = cg * 2 + ((ks >> 2) & 1);
        float cst = 0.f;

        for (int t = 0; t < 256; ++t) {
            float xgv = xg0[(size_t)t * 16384 + xgoff];   // issues pre-poll
            if (t > 0 && tid < 64) {
                int gd = 1 << 20;
                while (aloadi(&flags[tid * FSTR]) < t && --gd) {}
            }
            __syncthreads();
            // h0[t]: coalesced u64 loads + sentinel verify (rare retry)
            unsigned long long hv[4][8];
            int gd = 1 << 16;
            for (;;) {
#pragma unroll
                for (int bi = 0; bi < 4; ++bi) {
                    const float* hb = h0s + (size_t)t * 4096 + (bg * 4 + bi) * 512 + ks * 2;
#pragma unroll
                    for (int q = 0; q < 8; ++q)
                        hv[bi][q] = aload64(hb + q * 64);
                }
                unsigned bad = 0;
#pragma unroll
                for (int bi = 0; bi < 4; ++bi)
#pragma unroll
                    for (int q = 0; q < 8; ++q) bad |= sent_in(hv[bi][q]);
                if (!__any((int)bad) || --gd <= 0) break;
            }
            float2 acc[4][2][4];
#pragma unroll
            for (int g = 0; g < 4; ++g)
#pragma unroll
                for (int e = 0; e < 2; ++e)
#pragma unroll
                    for (int bi = 0; bi < 4; ++bi) acc[g][e][bi] = make_float2(0.f, 0.f);
#pragma unroll
            for (int q = 0; q < 8; ++q)
#pragma unroll
                for (int bi = 0; bi < 4; ++bi) {
                    float2 h2 = unpack64(hv[bi][q]);
#pragma unroll
                    for (int g = 0; g < 4; ++g)
#pragma unroll
                        for (int e = 0; e < 2; ++e) {
                            acc[g][e][bi].x = fmaf(W2[g][e][q].x, h2.x, acc[g][e][bi].x);
                            acc[g][e][bi].y = fmaf(W2[g][e][q].y, h2.y, acc[g][e][bi].y);
                        }
                }
            float s[32];
#pragma unroll
            for (int g = 0; g < 4; ++g)
#pragma unroll
                for (int e = 0; e < 2; ++e)
#pragma unroll
                    for (int bi = 0; bi < 4; ++bi)
                        s[g * 8 + e * 4 + bi] = acc[g][e][bi].x + acc[g][e][bi].y;
            // tree reduce: 5 levels, lane-bit k <-> value-bit k; lane ks ends with value ks
#pragma unroll
            for (int i = 0; i < 16; ++i) {
                float t_ = (ks & 16) ? s[i] : s[i + 16];
                float k_ = (ks & 16) ? s[i + 16] : s[i];
                s[i] = k_ + __shfl_xor(t_, 16);
            }
#pragma unroll
            for (int i = 0; i < 8; ++i) {
                float t_ = (ks & 8) ? s[i] : s[i + 8];
                float k_ = (ks & 8) ? s[i + 8] : s[i];
                s[i] = k_ + __shfl_xor(t_, 8);
            }
#pragma unroll
            for (int i = 0; i < 4; ++i) {
                float t_ = (ks & 4) ? s[i] : s[i + 4];
                float k_ = (ks & 4) ? s[i + 4] : s[i];
                s[i] = k_ + __shfl_xor(t_, 4);
            }
#pragma unroll
            for (int i = 0; i < 2; ++i) {
                float t_ = (ks & 2) ? s[i] : s[i + 2];
                float k_ = (ks & 2) ? s[i + 2] : s[i];
                s[i] = k_ + __shfl_xor(t_, 2);
            }
            {
                float t_ = (ks & 1) ? s[0] : s[1];
                float k_ = (ks & 1) ? s[1] : s[0];
                s[0] = k_ + __shfl_xor(t_, 1);
            }
            float red = s[0] + xgv;               // complete gate value v=ks
            float fgv = __shfl_xor(red, 8);       // v+8  (f gate)
            float ggv = __shfl_xor(red, 16);      // v+16 (g gate)
            float ogv = __shfl_xor(red, 24);      // v+24 (o gate)
            if (ks < 8) {
                cst = sigmf(fgv) * cst + sigmf(red) * tanhf(ggv);
                float hval = sigmf(ogv) * tanhf(cst);
                astore32(h0s + (size_t)(t + 1) * 4096 + ob * 512 + wg0 * 8 + ou, hval);
            }
            // no vmcnt drain: barrier only orders ISSUE; sentinel verify at the
            // consumer covers flag-before-data visibility.
            __syncthreads();
            if (tid == 0) astorei(&flags[wg0 * FSTR], t + 1);
        }
    } else {
        // ----- layer 1: 4 units (wg1*4 ..+3), K=1024 over [h0_{t+1} ; h1_t] -----
        const int wg1 = wg - 64;
        const int w = tid >> 6;
        const int cg = w >> 1, bgv = w & 1;
        const int ks = tid & 63;          // k = q*128 + ks*2 + {0,1}
        float2 W2[4][2][8];
#pragma unroll
        for (int g = 0; g < 4; ++g)
#pragma unroll
            for (int e = 0; e < 2; ++e) {
                const size_t ro = (size_t)(g * 512 + wg1 * 4 + cg * 2 + e) * 512 + ks * 2;
#pragma unroll
                for (int q = 0; q < 4; ++q)
                    W2[g][e][q] = *(const float2*)(wih1 + ro + q * 128);
#pragma unroll
                for (int q = 4; q < 8; ++q)
                    W2[g][e][q] = *(const float2*)(whh1 + ro + (q - 4) * 128);
            }
        // value mapping after tree: v4=ks5, v3=ks3, v2=ks2, v1=ks1, v0=ks0 (ks4 spare)
        const int vg = (((ks >> 5) & 1) << 1) | ((ks >> 3) & 1);
        const int ve = (ks >> 2) & 1, vbi = ks & 3;
        const int rv = vg * 512 + wg1 * 4 + cg * 2 + ve;
        const float biasv = bih1[rv] + bhh1[rv];
        const int ob = bgv * 4 + (ks & 3);
        const int ou = cg * 2 + ((ks >> 2) & 1);
        float cst = 0.f;

        for (int t = 0; t < 256; ++t) {
            if (tid < 64) {
                int gd = 1 << 20;
                while (aloadi(&flags[tid * FSTR]) < t + 1 && --gd) {}
            } else if (tid < 192 && t > 0) {
                int gd = 1 << 20;
                while (aloadi(&flags[tid * FSTR]) < t && --gd) {}   // 64+wg1 == tid
            }
            __syncthreads();
            // [h0_{t+1} ; h1_t] + sentinel verify
            unsigned long long hv[4][8];
            int gd = 1 << 16;
            for (;;) {
#pragma unroll
                for (int bi = 0; bi < 4; ++bi) {
                    const float* h0b = h0s + (size_t)(t + 1) * 4096 + (bgv * 4 + bi) * 512 + ks * 2;
                    const float* h1b = h1s + (size_t)t * 4096 + (bgv * 4 + bi) * 512 + ks * 2;
#pragma unroll
                    for (int q = 0; q < 4; ++q) hv[bi][q] = aload64(h0b + q * 128);
#pragma unroll
                    for (int q = 4; q < 8; ++q) hv[bi][q] = aload64(h1b + (q - 4) * 128);
                }
                unsigned bad = 0;
#pragma unroll
                for (int bi = 0; bi < 4; ++bi)
#pragma unroll
                    for (int q = 0; q < 8; ++q) bad |= sent_in(hv[bi][q]);
                if (!__any((int)bad) || --gd <= 0) break;
            }
            float2 acc[4][2][4];
#pragma unroll
            for (int g = 0; g < 4; ++g)
#pragma unroll
                for (int e = 0; e < 2; ++e)
#pragma unroll
                    for (int bi = 0; bi < 4; ++bi) acc[g][e][bi] = make_float2(0.f, 0.f);
#pragma unroll
            for (int q = 0; q < 8; ++q)
#pragma unroll
                for (int bi = 0; bi < 4; ++bi) {
                    float2 h2 = unpack64(hv[bi][q]);
#pragma unroll
                    for (int g = 0; g < 4; ++g)
#pragma unroll
                        for (int e = 0; e < 2; ++e) {
                            acc[g][e][bi].x = fmaf(W2[g][e][q].x, h2.x, acc[g][e][bi].x);
                            acc[g][e][bi].y = fmaf(W2[g][e][q].y, h2.y, acc[g][e][bi].y);
                        }
                }
            float s[32];
#pragma unroll
            for (int g = 0; g < 4; ++g)
#pragma unroll
                for (int e = 0; e < 2; ++e)
#pragma unroll
                    for (int bi = 0; bi < 4; ++bi)
                        s[g * 8 + e * 4 + bi] = acc[g][e][bi].x + acc[g][e][bi].y;
            // level A: lane bit5 <-> value bit4
#pragma unroll
            for (int i = 0; i < 16; ++i) {
                float t_ = (ks & 32) ? s[i] : s[i + 16];
                float k_ = (ks & 32) ? s[i + 16] : s[i];
                s[i] = k_ + __shfl_xor(t_, 32);
            }
#pragma unroll
            for (int i = 0; i < 8; ++i) {
                float t_ = (ks & 8) ? s[i] : s[i + 8];
                float k_ = (ks & 8) ? s[i + 8] : s[i];
                s[i] = k_ + __shfl_xor(t_, 8);
            }
#pragma unroll
            for (int i = 0; i < 4; ++i) {
                float t_ = (ks & 4) ? s[i] : s[i + 4];
                float k_ = (ks & 4) ? s[i + 4] : s[i];
                s[i] = k_ + __shfl_xor(t_, 4);
            }
#pragma unroll
            for (int i = 0; i < 2; ++i) {
                float t_ = (ks & 2) ? s[i] : s[i + 2];
                float k_ = (ks & 2) ? s[i + 2] : s[i];
                s[i] = k_ + __shfl_xor(t_, 2);
            }
            {
                float t_ = (ks & 1) ? s[0] : s[1];
                float k_ = (ks & 1) ? s[1] : s[0];
                s[0] = k_ + __shfl_xor(t_, 1);
            }
            // lane bit4 is spare; (l, l^16) hold half-sums of the same value.
            s[0] += __shfl_xor(s[0], 16);
            float red = s[0] + biasv;
            float fgv = __shfl_xor(red, 8);       // flip v3 -> lane bit3
            float ggv = __shfl_xor(red, 32);      // flip v4 -> lane bit5
            float ogv = __shfl_xor(red, 40);      // flip v4,v3
            if (ks < 8) {
                cst = sigmf(fgv) * cst + sigmf(red) * tanhf(ggv);
                float hval = sigmf(ogv) * tanhf(cst);
                astore32(h1s + (size_t)(t + 1) * 4096 + ob * 512 + wg1 * 4 + ou, hval);
            }
            __syncthreads();
            if (tid == 0) astorei(&flags[(64 + wg1) * FSTR], t + 1);
        }
    }
}

// ---------------- attention (collapsed): ctx[b] = softmax(enc_p[b,:]) @ enc[b] ----------------
__launch_bounds__(256)
__global__ void attn_kernel(const float* __restrict__ enc, const float* __restrict__ attn_w,
                            float* __restrict__ ctx) {
    __shared__ float aw[512];
    __shared__ float pr[256];
    __shared__ float red[8];
    const int b = blockIdx.x, tid = threadIdx.x;
    if (tid < 128) ((float4*)aw)[tid] = ((const float4*)(attn_w + 512))[tid];
    __syncthreads();
    const float* er = enc + (size_t)(b * 256 + tid) * 512;
    float4 a4 = make_float4(0, 0, 0, 0);
#pragma unroll 8
    for (int i = 0; i < 128; ++i) {
        float4 e4 = *(const float4*)(er + i * 4);
        float4 w4 = *(const float4*)(aw + i * 4);
        fma4(a4, e4, w4);
    }
    float v = hsum4(a4);
    float m = v;
#pragma unroll
    for (int off = 32; off > 0; off >>= 1) m = fmaxf(m, __shfl_xor(m, off));
    if ((tid & 63) == 0) red[tid >> 6] = m;
    __syncthreads();
    if (tid == 0) red[4] = fmaxf(fmaxf(red[0], red[1]), fmaxf(red[2], red[3]));
    __syncthreads();
    float e = expf(v - red[4]);
    pr[tid] = e;
    float s = e;
#pragma unroll
    for (int off = 32; off > 0; off >>= 1) s += __shfl_xor(s, off);
    if ((tid & 63) == 0) red[tid >> 6] = s;
    __syncthreads();
    if (tid == 0) red[5] = red[0] + red[1] + red[2] + red[3];
    __syncthreads();
    float inv = 1.f / red[5];
    for (int hh = tid; hh < 512; hh += 256) {
        float acc = 0.f;
#pragma unroll 8
        for (int s2 = 0; s2 < 256; ++s2)
            acc = fmaf(pr[s2], enc[(size_t)(b * 256 + s2) * 512 + hh], acc);
        ctx[b * 512 + hh] = acc * inv;
    }
}

__global__ void bcast_ctx_kernel(const float* __restrict__ ctx, float* __restrict__ outc) {
    int fi = blockIdx.x * 256 + threadIdx.x;       // f4 idx, total 262144
    int h4 = fi & 127;
    int b = fi >> 15;
    ((float4*)outc)[fi] = ((const float4*)ctx)[b * 128 + h4];
}

// ---------------- output head: (b,t) row -> 10 logits ----------------
__launch_bounds__(256)
__global__ void out_proj_kernel(const float* __restrict__ h1s, const float* __restrict__ ow,
                                const float* __restrict__ ob, float* __restrict__ out) {
    int lane = threadIdx.x & 63;
    int m = blockIdx.x * 4 + (threadIdx.x >> 6);    // 0..2047, m = t*8+b
    int t = m >> 3, b = m & 7;
    const float* dr = h1s + (size_t)(t + 1) * 4096 + b * 512 + lane * 8;
    float4 d0 = *(const float4*)dr;
    float4 d1 = *(const float4*)(dr + 4);
    float acc[10];
#pragma unroll
    for (int v = 0; v < 10; ++v) {
        const float* wr = ow + v * 512 + lane * 8;
        float4 w0 = *(const float4*)wr, w1 = *(const float4*)(wr + 4);
        acc[v] = d0.x * w0.x + d0.y * w0.y + d0.z * w0.z + d0.w * w0.w +
                 d1.x * w1.x + d1.y * w1.y + d1.z * w1.z + d1.w * w1.w;
    }
#pragma unroll
    for (int v = 0; v < 10; ++v)
#pragma unroll
        for (int off = 32; off > 0; off >>= 1) acc[v] += __shfl_xor(acc[v], off);
    if (lane == 0) {
        float* o = out + (size_t)(b * 256 + t) * 10;
#pragma unroll
        for (int v = 0; v < 10; ++v) o[v] = acc[v] + ob[v];
    }
}

// ---------------- launch ----------------
extern "C" void kernel_launch(void* const* d_in, const int* in_sizes, int n_in,
                              void* d_out, int out_size, void* d_ws, size_t ws_size,
                              hipStream_t stream) {
    const int* src = (const int*)d_in[0];
    const int* tgt = (const int*)d_in[1];
    const float* emb = (const float*)d_in[2];
    const float* c1w = (const float*)d_in[3];
    const float* c1b = (const float*)d_in[4];
    const float* c2w = (const float*)d_in[5];
    const float* c2b = (const float*)d_in[6];
    const float* c3w = (const float*)d_in[7];
    const float* c3b = (const float*)d_in[8];
    const float* wih0 = (const float*)d_in[9];
    const float* whh0 = (const float*)d_in[10];
    const float* bih0 = (const float*)d_in[11];
    const float* bhh0 = (const float*)d_in[12];
    const float* wih1 = (const float*)d_in[13];
    const float* whh1 = (const float*)d_in[14];
    const float* bih1 = (const float*)d_in[15];
    const float* bhh1 = (const float*)d_in[16];
    const float* attn_w = (const float*)d_in[17];
    const float* out_w = (const float*)d_in[19];
    const float* out_b = (const float*)d_in[20];

    float* ws = (float*)d_ws;
    float* xb0 = ws + OXB0;
    float* xb1 = ws + OXB1;
    float* xb2 = ws + OXB2;
    float* enc = ws + OENC;
    float* wr1 = ws + OWR1;
    float* wr2 = ws + OWR2;
    float* wr3 = ws + OWR3;
    float* wr0 = ws + OWR0;
    float* etg = ws + OTGT;
    float* xg0 = ws + OXG0;
    float* h0s = ws + OH0S;
    float* h1s = ws + OH1S;
    float* ctx = ws + OCTX;
    int* flags = (int*)(ws + OFLG);
    float* outp = (float*)d_out;

    init_kernel<<<1024, 256, 0, stream>>>(ws, flags);
    embed_src_kernel<<<2052, 256, 0, stream>>>(src, emb, xb0);
    gather_tgt_kernel<<<512, 256, 0, stream>>>(tgt, emb, etg);
    tr_conv_kernel<<<768, 256, 0, stream>>>(c1w, wr1, 256, 256);
    tr_conv_kernel<<<1536, 256, 0, stream>>>(c2w, wr2, 512, 256);
    tr_conv_kernel<<<3072, 256, 0, stream>>>(c3w, wr3, 512, 512);
    tr_mat_kernel<<<2048, 256, 0, stream>>>(wih0, wr0, 2048, 256);

    // xg0 = embtgt @ wih0^T + bih0 + bhh0   (rows ordered t*8+b)
    gemm_kernel<<<dim3(32, 32, 1), 256, 0, stream>>>(etg, 0, 256, 256, wr0, 2048,
                                                     bih0, bhh0, xg0, 0, 0);
    // conv1 + relu + pool: (8,1026,256) -> (8,514,256)
    gemm_kernel<<<dim3(16, 4, 8), 256, 0, stream>>>(xb0, 262656, 256, 768, wr1, 256,
                                                    c1b, nullptr, xb1, 131584, 1);
    // conv2 + relu + pool: (8,514,256) -> (8,258,512)
    gemm_kernel<<<dim3(8, 8, 8), 256, 0, stream>>>(xb1, 131584, 256, 768, wr2, 512,
                                                   c2b, nullptr, xb2, 132096, 1);
    // conv3 + relu: (8,258,512) -> enc (8,256,512)
    gemm_kernel<<<dim3(4, 8, 8), 256, 0, stream>>>(xb2, 132096, 512, 1536, wr3, 512,
                                                   c3b, nullptr, enc, 131072, 2);
    // persistent 2-layer LSTM (no-drain publish + sentinel verify)
    lstm_kernel<<<192, 256, 0, stream>>>(xg0, whh0, wih1, whh1, bih1, bhh1,
                                         h0s, h1s, flags);
    // collapsed attention + context broadcast
    attn_kernel<<<8, 256, 0, stream>>>(enc, attn_w, ctx);
    bcast_ctx_kernel<<<1024, 256, 0, stream>>>(ctx, outp + 20480);
    // output logits
    out_proj_kernel<<<512, 256, 0, stream>>>(h1s, out_w, out_b, outp);
}

// Round 13
// 1403.956 us; speedup vs baseline: 1.6237x; 1.0073x over previous
//
#include <hip/hip_runtime.h>
#include <cstddef>

// ---------------- constants ----------------
// B=8, S=1024, T=256, E=256, H=512, Senc=256
constexpr int OXB0 = 0;                         // (8, 1026, 256) padded ch-last embed(src)
constexpr int OXB1 = OXB0 + 8 * 1026 * 256;     // (8, 514, 256) after conv1+pool
constexpr int OXB2 = OXB1 + 8 * 514 * 256;      // (8, 258, 512) after conv2+pool
constexpr int OENC = OXB2 + 8 * 258 * 512;      // (8, 256, 512) enc
constexpr int OWR1 = OENC + 8 * 256 * 512;      // 768x256   conv1 W^T
constexpr int OWR2 = OWR1 + 768 * 256;          // 768x512   conv2 W^T
constexpr int OWR3 = OWR2 + 768 * 512;          // 1536x512  conv3 W^T
constexpr int OWR0 = OWR3 + 1536 * 512;         // 256x2048  wih0^T
constexpr int OTGT = OWR0 + 256 * 2048;         // 2048x256  embed(tgt), row = t*8+b
constexpr int OXG0 = OTGT + 2048 * 256;         // 2048x2048 xg0
constexpr int OH0S = OXG0 + 2048 * 2048;        // 257*4096  h0 sequence
constexpr int OH1S = OH0S + 257 * 4096;         // 257*4096  h1 sequence
constexpr int OCTX = OH1S + 257 * 4096;         // 8*512 ctx per batch
constexpr int OFLG = OCTX + 8 * 512;            // 192*16 ints: per-block flags
constexpr int OCNT = OFLG + 192 * 16;           // 8 ints: encoder stage counters

constexpr int FSTR = 16;                        // 64B flag stride
constexpr unsigned SENT = 0x7FC0DEADu;          // NaN sentinel for h planes

__device__ __forceinline__ float hsum4(const float4& a) { return a.x + a.y + a.z + a.w; }
__device__ __forceinline__ float4 relu4(float4 v, const float4& bv) {
    v.x = fmaxf(v.x + bv.x, 0.f); v.y = fmaxf(v.y + bv.y, 0.f);
    v.z = fmaxf(v.z + bv.z, 0.f); v.w = fmaxf(v.w + bv.w, 0.f); return v;
}
__device__ __forceinline__ float4 max4(const float4& a, const float4& b) {
    float4 r; r.x = fmaxf(a.x, b.x); r.y = fmaxf(a.y, b.y);
    r.z = fmaxf(a.z, b.z); r.w = fmaxf(a.w, b.w); return r;
}
__device__ __forceinline__ float sigmf(float x) { return 1.f / (1.f + expf(-x)); }
__device__ __forceinline__ void fma4(float4& acc, const float4& a, const float4& b) {
    acc.x = fmaf(a.x, b.x, acc.x); acc.y = fmaf(a.y, b.y, acc.y);
    acc.z = fmaf(a.z, b.z, acc.z); acc.w = fmaf(a.w, b.w, acc.w);
}

__device__ __forceinline__ unsigned long long aload64(const float* p) {
    return __hip_atomic_load((const unsigned long long*)p, __ATOMIC_RELAXED,
                             __HIP_MEMORY_SCOPE_AGENT);
}
__device__ __forceinline__ void astore32(float* p, float v) {
    __hip_atomic_store((unsigned int*)p, __float_as_uint(v), __ATOMIC_RELAXED,
                       __HIP_MEMORY_SCOPE_AGENT);
}
__device__ __forceinline__ int aloadi(const int* p) {
    return __hip_atomic_load(p, __ATOMIC_RELAXED, __HIP_MEMORY_SCOPE_AGENT);
}
__device__ __forceinline__ void astorei(int* p, int v) {
    __hip_atomic_store(p, v, __ATOMIC_RELAXED, __HIP_MEMORY_SCOPE_AGENT);
}
__device__ __forceinline__ float2 unpack64(unsigned long long v) {
    float2 f;
    f.x = __uint_as_float((unsigned)v);
    f.y = __uint_as_float((unsigned)(v >> 32));
    return f;
}
__device__ __forceinline__ unsigned sent_in(unsigned long long v) {
    return ((unsigned)v == SENT) | ((unsigned)(v >> 32) == SENT);
}

// encoder stage sync (inside fused kernel): producer drains+barriers then RELEASE
// add (agent release = L2 writeback); consumer relaxed-polls then one ACQUIRE load
// (agent acquire = L2 invalidate) -> later normal loads see remote stores despite
// non-coherent per-XCD L2s.
__device__ __forceinline__ void stage_signal(int* cnt) {
    asm volatile("s_waitcnt vmcnt(0)" ::: "memory");
    __syncthreads();
    if (threadIdx.x == 0)
        __hip_atomic_fetch_add(cnt, 1, __ATOMIC_RELEASE, __HIP_MEMORY_SCOPE_AGENT);
}
__device__ __forceinline__ void stage_wait(int* cnt, int target) {
    if (threadIdx.x == 0) {
        int gd = 1 << 22;
        while (__hip_atomic_load(cnt, __ATOMIC_RELAXED, __HIP_MEMORY_SCOPE_AGENT) < target && --gd) {}
        (void)__hip_atomic_load(cnt, __ATOMIC_ACQUIRE, __HIP_MEMORY_SCOPE_AGENT);
    }
    __syncthreads();
}

// ---------------- init ----------------
__global__ void init_kernel(float* __restrict__ ws, int* __restrict__ flags,
                            int* __restrict__ cnts) {
    int idx = blockIdx.x * 256 + threadIdx.x;
    int stride = gridDim.x * 256;
    float sentf = __uint_as_float(SENT);
    for (int i = idx; i < 257 * 4096; i += stride) {
        float v = (i < 4096) ? 0.f : sentf;
        ws[OH0S + i] = v;
        ws[OH1S + i] = v;
    }
    for (int i = idx; i < 192 * FSTR; i += stride) flags[i] = 0;
    for (int i = idx; i < 8; i += stride) cnts[i] = 0;
    for (int i = idx; i < 8 * 2 * 256; i += stride) {
        int b = i >> 9, rr = (i >> 8) & 1, c = i & 255;
        ws[OXB1 + b * 131584 + (rr ? 513 : 0) * 256 + c] = 0.f;
    }
    for (int i = idx; i < 8 * 2 * 512; i += stride) {
        int b = i >> 10, rr = (i >> 9) & 1, c = i & 511;
        ws[OXB2 + b * 132096 + (rr ? 257 : 0) * 512 + c] = 0.f;
    }
}

// ---------------- gather tgt (pre-LSTM critical path) ----------------
__global__ void gather_tgt_kernel(const int* __restrict__ tgt, const float* __restrict__ emb,
                                  float* __restrict__ et) {
    int fi = blockIdx.x * 256 + threadIdx.x;          // total 2048*64
    int e4 = fi & 63;
    int r = fi >> 6;                                  // m = t*8 + b
    int t = r >> 3, b = r & 7;
    int row = tgt[b * 256 + t];
    *(float4*)(et + (size_t)fi * 4) = *(const float4*)(emb + row * 256 + e4 * 4);
}

__global__ void tr_mat_kernel(const float* __restrict__ w, float* __restrict__ wr,
                              int N, int K) {
    int idx = blockIdx.x * 256 + threadIdx.x;
    int n = idx / K;
    int k = idx - n * K;
    wr[k * N + n] = w[idx];
}

// ---------------- GEMM tile as device function ----------------
// C tile (64x64) at (bx,by,bz): sum_k A[bz][m*RS+k]*Bw[k*N+n]; modes as before.
__device__ void gemm_tile(const float* __restrict__ A, int aBS, int RS, int K,
                          const float* __restrict__ Bw, int N,
                          const float* __restrict__ bias, const float* __restrict__ bias2,
                          float* __restrict__ out, int oBS, int mode,
                          int bx, int by, int bz, float* As, float* Bs) {
    const int tid = threadIdx.x;
    const int tl = tid & 15, tco = tid >> 4;
    const int m0 = bx * 64, n0 = by * 64;
    const float* Ab = A + (size_t)bz * aBS;
    float4 acc0 = make_float4(0, 0, 0, 0), acc1 = acc0, acc2 = acc0, acc3 = acc0;

    for (int k0 = 0; k0 < K; k0 += 32) {
#pragma unroll
        for (int p = 0; p < 2; ++p) {
            int f = p * 256 + tid;
            int row = f >> 3, j4 = f & 7;
            float4 av = *(const float4*)(Ab + (size_t)(m0 + row) * RS + k0 + j4 * 4);
            int kb = j4 * 4;
            As[(kb + 0) * 68 + row] = av.x;
            As[(kb + 1) * 68 + row] = av.y;
            As[(kb + 2) * 68 + row] = av.z;
            As[(kb + 3) * 68 + row] = av.w;
        }
#pragma unroll
        for (int p = 0; p < 2; ++p) {
            int f = p * 256 + tid;
            int kk = f >> 4, j4 = f & 15;
            *(float4*)(&Bs[kk * 64 + j4 * 4]) =
                *(const float4*)(Bw + (size_t)(k0 + kk) * N + n0 + j4 * 4);
        }
        __syncthreads();
#pragma unroll
        for (int kk = 0; kk < 32; ++kk) {
            float4 a4 = *(const float4*)(&As[kk * 68 + tl * 4]);
            float4 b4 = *(const float4*)(&Bs[kk * 64 + tco * 4]);
            acc0.x = fmaf(a4.x, b4.x, acc0.x); acc0.y = fmaf(a4.x, b4.y, acc0.y);
            acc0.z = fmaf(a4.x, b4.z, acc0.z); acc0.w = fmaf(a4.x, b4.w, acc0.w);
            acc1.x = fmaf(a4.y, b4.x, acc1.x); acc1.y = fmaf(a4.y, b4.y, acc1.y);
            acc1.z = fmaf(a4.y, b4.z, acc1.z); acc1.w = fmaf(a4.y, b4.w, acc1.w);
            acc2.x = fmaf(a4.z, b4.x, acc2.x); acc2.y = fmaf(a4.z, b4.y, acc2.y);
            acc2.z = fmaf(a4.z, b4.z, acc2.z); acc2.w = fmaf(a4.z, b4.w, acc2.w);
            acc3.x = fmaf(a4.w, b4.x, acc3.x); acc3.y = fmaf(a4.w, b4.y, acc3.y);
            acc3.z = fmaf(a4.w, b4.z, acc3.z); acc3.w = fmaf(a4.w, b4.w, acc3.w);
        }
        __syncthreads();
    }

    int nb = n0 + tco * 4;
    float4 bv;
    bv.x = bias[nb + 0]; bv.y = bias[nb + 1]; bv.z = bias[nb + 2]; bv.w = bias[nb + 3];
    if (bias2) { bv.x += bias2[nb + 0]; bv.y += bias2[nb + 1]; bv.z += bias2[nb + 2]; bv.w += bias2[nb + 3]; }

    if (mode == 0) {
        float4 v0 = acc0, v1 = acc1, v2 = acc2, v3 = acc3;
        v0.x += bv.x; v0.y += bv.y; v0.z += bv.z; v0.w += bv.w;
        v1.x += bv.x; v1.y += bv.y; v1.z += bv.z; v1.w += bv.w;
        v2.x += bv.x; v2.y += bv.y; v2.z += bv.z; v2.w += bv.w;
        v3.x += bv.x; v3.y += bv.y; v3.z += bv.z; v3.w += bv.w;
        int mr = m0 + tl * 4;
        *(float4*)(out + (size_t)(mr + 0) * N + nb) = v0;
        *(float4*)(out + (size_t)(mr + 1) * N + nb) = v1;
        *(float4*)(out + (size_t)(mr + 2) * N + nb) = v2;
        *(float4*)(out + (size_t)(mr + 3) * N + nb) = v3;
    } else if (mode == 1) {
        float4 v0 = relu4(acc0, bv), v1 = relu4(acc1, bv), v2 = relu4(acc2, bv), v3 = relu4(acc3, bv);
        float4 p0 = max4(v0, v1), p1 = max4(v2, v3);
        int lout = (m0 + tl * 4) >> 1;
        float* ob = out + (size_t)bz * oBS + (size_t)(1 + lout) * N + nb;
        *(float4*)ob = p0;
        *(float4*)(ob + N) = p1;
    } else {
        float4 v0 = relu4(acc0, bv), v1 = relu4(acc1, bv), v2 = relu4(acc2, bv), v3 = relu4(acc3, bv);
        int mr = m0 + tl * 4;
        float* ob = out + (size_t)bz * oBS + (size_t)mr * N + nb;
        *(float4*)(ob + 0 * N) = v0;
        *(float4*)(ob + 1 * N) = v1;
        *(float4*)(ob + 2 * N) = v2;
        *(float4*)(ob + 3 * N) = v3;
    }
}

// standalone GEMM wrapper (used for xg0, pre-LSTM)
__launch_bounds__(256)
__global__ void gemm_kernel(const float* __restrict__ A, int aBS, int RS, int K,
                            const float* __restrict__ Bw, int N,
                            const float* __restrict__ bias, const float* __restrict__ bias2,
                            float* __restrict__ out, int oBS, int mode) {
    __shared__ float As[32 * 68];
    __shared__ float Bs[32 * 64];
    gemm_tile(A, aBS, RS, K, Bw, N, bias, bias2, out, oBS, mode,
              blockIdx.x, blockIdx.y, blockIdx.z, As, Bs);
}

// ---------------- fused persistent kernel: LSTM (192 blocks) + encoder (64 blocks) ----------------
// Blocks 0..63: LSTM layer0 (v9 protocol, measured == best). Blocks 64..191: layer1.
// Blocks 192..255: CNN encoder pipeline (embed_src + W transposes -> conv1 -> conv2
// -> conv3 -> attention -> ctx broadcast), staged with release/acquire counters.
// Encoder (~6.5 GFLOP on 64 CUs ~= 0.5-0.8ms) hides under the 1.17ms latency-bound
// LSTM, which uses <25% of its 192 CUs' VALU and 1.4% of HBM.
__launch_bounds__(256, 1)
__global__ void lstm_fused_kernel(const float* __restrict__ xg0,
                                  const float* __restrict__ whh0,
                                  const float* __restrict__ wih1,
                                  const float* __restrict__ whh1,
                                  const float* __restrict__ bih1,
                                  const float* __restrict__ bhh1,
                                  float* __restrict__ h0s, float* __restrict__ h1s,
                                  int* __restrict__ flags, int* __restrict__ cnts,
                                  const int* __restrict__ src,
                                  const float* __restrict__ emb,
                                  const float* __restrict__ c1w, const float* __restrict__ c1b,
                                  const float* __restrict__ c2w, const float* __restrict__ c2b,
                                  const float* __restrict__ c3w, const float* __restrict__ c3b,
                                  const float* __restrict__ attn_w,
                                  float* __restrict__ ws, float* __restrict__ outp) {
    __shared__ float As[32 * 68];
    __shared__ float Bs[32 * 64];
    const int tid = threadIdx.x;
    const int wg = blockIdx.x;

    if (wg < 64) {
        // ----- layer 0: 8 units (wg0*8 ..+7), K=512 -----
        const int wg0 = wg;
        const int cg = tid >> 6;
        const int bg = (tid >> 5) & 1;
        const int ks = tid & 31;
        float2 W2[4][2][8];
#pragma unroll
        for (int g = 0; g < 4; ++g)
#pragma unroll
            for (int e = 0; e < 2; ++e) {
                const float* wr = whh0 + (size_t)(g * 512 + wg0 * 8 + cg * 2 + e) * 512 + ks * 2;
#pragma unroll
                for (int q = 0; q < 8; ++q)
                    W2[g][e][q] = *(const float2*)(wr + q * 64);
            }
        const int vg = ks >> 3, ve = (ks >> 2) & 1, vbi = ks & 3;
        const int vb = bg * 4 + vbi;
        const size_t xgoff = (size_t)vb * 2048 + vg * 512 + wg0 * 8 + cg * 2 + ve;
        const int ob = bg * 4 + (ks & 3);
        const int ou = cg * 2 + ((ks >> 2) & 1);
        float cst = 0.f;

        for (int t = 0; t < 256; ++t) {
            float xgv = xg0[(size_t)t * 16384 + xgoff];
            if (t > 0 && tid < 64) {
                int gd = 1 << 20;
                while (aloadi(&flags[tid * FSTR]) < t && --gd) {}
            }
            __syncthreads();
            unsigned long long hv[4][8];
            int gd = 1 << 16;
            for (;;) {
#pragma unroll
                for (int bi = 0; bi < 4; ++bi) {
                    const float* hb = h0s + (size_t)t * 4096 + (bg * 4 + bi) * 512 + ks * 2;
#pragma unroll
                    for (int q = 0; q < 8; ++q)
                        hv[bi][q] = aload64(hb + q * 64);
                }
                unsigned bad = 0;
#pragma unroll
                for (int bi = 0; bi < 4; ++bi)
#pragma unroll
                    for (int q = 0; q < 8; ++q) bad |= sent_in(hv[bi][q]);
                if (!__any((int)bad) || --gd <= 0) break;
            }
            float2 acc[4][2][4];
#pragma unroll
            for (int g = 0; g < 4; ++g)
#pragma unroll
                for (int e = 0; e < 2; ++e)
#pragma unroll
                    for (int bi = 0; bi < 4; ++bi) acc[g][e][bi] = make_float2(0.f, 0.f);
#pragma unroll
            for (int q = 0; q < 8; ++q)
#pragma unroll
                for (int bi = 0; bi < 4; ++bi) {
                    float2 h2 = unpack64(hv[bi][q]);
#pragma unroll
                    for (int g = 0; g < 4; ++g)
#pragma unroll
                        for (int e = 0; e < 2; ++e) {
                            acc[g][e][bi].x = fmaf(W2[g][e][q].x, h2.x, acc[g][e][bi].x);
                            acc[g][e][bi].y = fmaf(W2[g][e][q].y, h2.y, acc[g][e][bi].y);
                        }
                }
            float s[32];
#pragma unroll
            for (int g = 0; g < 4; ++g)
#pragma unroll
                for (int e = 0; e < 2; ++e)
#pragma unroll
                    for (int bi = 0; bi < 4; ++bi)
                        s[g * 8 + e * 4 + bi] = acc[g][e][bi].x + acc[g][e][bi].y;
#pragma unroll
            for (int i = 0; i < 16; ++i) {
                float t_ = (ks & 16) ? s[i] : s[i + 16];
                float k_ = (ks & 16) ? s[i + 16] : s[i];
                s[i] = k_ + __shfl_xor(t_, 16);
            }
#pragma unroll
            for (int i = 0; i < 8; ++i) {
                float t_ = (ks & 8) ? s[i] : s[i + 8];
                float k_ = (ks & 8) ? s[i + 8] : s[i];
                s[i] = k_ + __shfl_xor(t_, 8);
            }
#pragma unroll
            for (int i = 0; i < 4; ++i) {
                float t_ = (ks & 4) ? s[i] : s[i + 4];
                float k_ = (ks & 4) ? s[i + 4] : s[i];
                s[i] = k_ + __shfl_xor(t_, 4);
            }
#pragma unroll
            for (int i = 0; i < 2; ++i) {
                float t_ = (ks & 2) ? s[i] : s[i + 2];
                float k_ = (ks & 2) ? s[i + 2] : s[i];
                s[i] = k_ + __shfl_xor(t_, 2);
            }
            {
                float t_ = (ks & 1) ? s[0] : s[1];
                float k_ = (ks & 1) ? s[1] : s[0];
                s[0] = k_ + __shfl_xor(t_, 1);
            }
            float red = s[0] + xgv;
            float fgv = __shfl_xor(red, 8);
            float ggv = __shfl_xor(red, 16);
            float ogv = __shfl_xor(red, 24);
            if (ks < 8) {
                cst = sigmf(fgv) * cst + sigmf(red) * tanhf(ggv);
                float hval = sigmf(ogv) * tanhf(cst);
                astore32(h0s + (size_t)(t + 1) * 4096 + ob * 512 + wg0 * 8 + ou, hval);
            }
            __syncthreads();
            if (tid == 0) astorei(&flags[wg0 * FSTR], t + 1);
        }
    } else if (wg < 192) {
        // ----- layer 1: 4 units (wg1*4 ..+3), K=1024 -----
        const int wg1 = wg - 64;
        const int w = tid >> 6;
        const int cg = w >> 1, bgv = w & 1;
        const int ks = tid & 63;
        float2 W2[4][2][8];
#pragma unroll
        for (int g = 0; g < 4; ++g)
#pragma unroll
            for (int e = 0; e < 2; ++e) {
                const size_t ro = (size_t)(g * 512 + wg1 * 4 + cg * 2 + e) * 512 + ks * 2;
#pragma unroll
                for (int q = 0; q < 4; ++q)
                    W2[g][e][q] = *(const float2*)(wih1 + ro + q * 128);
#pragma unroll
                for (int q = 4; q < 8; ++q)
                    W2[g][e][q] = *(const float2*)(whh1 + ro + (q - 4) * 128);
            }
        const int vg = (((ks >> 5) & 1) << 1) | ((ks >> 3) & 1);
        const int ve = (ks >> 2) & 1, vbi = ks & 3;
        const int rv = vg * 512 + wg1 * 4 + cg * 2 + ve;
        const float biasv = bih1[rv] + bhh1[rv];
        const int ob = bgv * 4 + (ks & 3);
        const int ou = cg * 2 + ((ks >> 2) & 1);
        float cst = 0.f;

        for (int t = 0; t < 256; ++t) {
            if (tid < 64) {
                int gd = 1 << 20;
                while (aloadi(&flags[tid * FSTR]) < t + 1 && --gd) {}
            } else if (tid < 192 && t > 0) {
                int gd = 1 << 20;
                while (aloadi(&flags[tid * FSTR]) < t && --gd) {}
            }
            __syncthreads();
            unsigned long long hv[4][8];
            int gd = 1 << 16;
            for (;;) {
#pragma unroll
                for (int bi = 0; bi < 4; ++bi) {
                    const float* h0b = h0s + (size_t)(t + 1) * 4096 + (bgv * 4 + bi) * 512 + ks * 2;
                    const float* h1b = h1s + (size_t)t * 4096 + (bgv * 4 + bi) * 512 + ks * 2;
#pragma unroll
                    for (int q = 0; q < 4; ++q) hv[bi][q] = aload64(h0b + q * 128);
#pragma unroll
                    for (int q = 4; q < 8; ++q) hv[bi][q] = aload64(h1b + (q - 4) * 128);
                }
                unsigned bad = 0;
#pragma unroll
                for (int bi = 0; bi < 4; ++bi)
#pragma unroll
                    for (int q = 0; q < 8; ++q) bad |= sent_in(hv[bi][q]);
                if (!__any((int)bad) || --gd <= 0) break;
            }
            float2 acc[4][2][4];
#pragma unroll
            for (int g = 0; g < 4; ++g)
#pragma unroll
                for (int e = 0; e < 2; ++e)
#pragma unroll
                    for (int bi = 0; bi < 4; ++bi) acc[g][e][bi] = make_float2(0.f, 0.f);
#pragma unroll
            for (int q = 0; q < 8; ++q)
#pragma unroll
                for (int bi = 0; bi < 4; ++bi) {
                    float2 h2 = unpack64(hv[bi][q]);
#pragma unroll
                    for (int g = 0; g < 4; ++g)
#pragma unroll
                        for (int e = 0; e < 2; ++e) {
                            acc[g][e][bi].x = fmaf(W2[g][e][q].x, h2.x, acc[g][e][bi].x);
                            acc[g][e][bi].y = fmaf(W2[g][e][q].y, h2.y, acc[g][e][bi].y);
                        }
                }
            float s[32];
#pragma unroll
            for (int g = 0; g < 4; ++g)
#pragma unroll
                for (int e = 0; e < 2; ++e)
#pragma unroll
                    for (int bi = 0; bi < 4; ++bi)
                        s[g * 8 + e * 4 + bi] = acc[g][e][bi].x + acc[g][e][bi].y;
#pragma unroll
            for (int i = 0; i < 16; ++i) {
                float t_ = (ks & 32) ? s[i] : s[i + 16];
                float k_ = (ks & 32) ? s[i + 16] : s[i];
                s[i] = k_ + __shfl_xor(t_, 32);
            }
#pragma unroll
            for (int i = 0; i < 8; ++i) {
                float t_ = (ks & 8) ? s[i] : s[i + 8];
                float k_ = (ks & 8) ? s[i + 8] : s[i];
                s[i] = k_ + __shfl_xor(t_, 8);
            }
#pragma unroll
            for (int i = 0; i < 4; ++i) {
                float t_ = (ks & 4) ? s[i] : s[i + 4];
                float k_ = (ks & 4) ? s[i + 4] : s[i];
                s[i] = k_ + __shfl_xor(t_, 4);
            }
#pragma unroll
            for (int i = 0; i < 2; ++i) {
                float t_ = (ks & 2) ? s[i] : s[i + 2];
                float k_ = (ks & 2) ? s[i + 2] : s[i];
                s[i] = k_ + __shfl_xor(t_, 2);
            }
            {
                float t_ = (ks & 1) ? s[0] : s[1];
                float k_ = (ks & 1) ? s[1] : s[0];
                s[0] = k_ + __shfl_xor(t_, 1);
            }
            s[0] += __shfl_xor(s[0], 16);
            float red = s[0] + biasv;
            float fgv = __shfl_xor(red, 8);
            float ggv = __shfl_xor(red, 32);
            float ogv = __shfl_xor(red, 40);
            if (ks < 8) {
                cst = sigmf(fgv) * cst + sigmf(red) * tanhf(ggv);
                float hval = sigmf(ogv) * tanhf(cst);
                astore32(h1s + (size_t)(t + 1) * 4096 + ob * 512 + wg1 * 4 + ou, hval);
            }
            __syncthreads();
            if (tid == 0) astorei(&flags[(64 + wg1) * FSTR], t + 1);
        }
    } else {
        // ----- encoder pipeline on 64 blocks -----
        const int eb = wg - 192;          // 0..63
        const int gidx = eb * 256 + tid;  // 0..16383
        float* xb0 = ws + OXB0;
        float* xb1 = ws + OXB1;
        float* xb2 = ws + OXB2;
        float* enc = ws + OENC;
        float* wr1 = ws + OWR1;
        float* wr2 = ws + OWR2;
        float* wr3 = ws + OWR3;
        float* ctx = ws + OCTX;

        // stage A: embed(src) scatter + conv weight transposes
        for (int fi = gidx; fi < 8 * 1026 * 64; fi += 16384) {
            int e4 = fi & 63;
            int r = fi >> 6;
            int b = r / 1026;
            int p = r - b * 1026;
            float4 v = make_float4(0.f, 0.f, 0.f, 0.f);
            if (p > 0 && p < 1025) {
                int row = src[b * 1024 + (p - 1)];
                v = *(const float4*)(emb + row * 256 + e4 * 4);
            }
            *(float4*)(xb0 + (size_t)fi * 4) = v;
        }
        for (int i = gidx; i < 256 * 256 * 3; i += 16384) {
            int co = i / (256 * 3); int rem = i - co * 256 * 3;
            int ci = rem / 3; int dk = rem - ci * 3;
            wr1[(dk * 256 + ci) * 256 + co] = c1w[i];
        }
        for (int i = gidx; i < 512 * 256 * 3; i += 16384) {
            int co = i / (256 * 3); int rem = i - co * 256 * 3;
            int ci = rem / 3; int dk = rem - ci * 3;
            wr2[(dk * 256 + ci) * 512 + co] = c2w[i];
        }
        for (int i = gidx; i < 512 * 512 * 3; i += 16384) {
            int co = i / (512 * 3); int rem = i - co * 512 * 3;
            int ci = rem / 3; int dk = rem - ci * 3;
            wr3[(dk * 512 + ci) * 512 + co] = c3w[i];
        }
        stage_signal(&cnts[0]);
        stage_wait(&cnts[0], 64);
        // stage B: conv1 (512 tiles, 8 per block), grid logical (16,4,8)
        for (int j = 0; j < 8; ++j) {
            int t = eb * 8 + j;
            gemm_tile(xb0, 262656, 256, 768, wr1, 256, c1b, nullptr, xb1, 131584, 1,
                      t & 15, (t >> 4) & 3, t >> 6, As, Bs);
        }
        stage_signal(&cnts[1]);
        stage_wait(&cnts[1], 64);
        // stage C: conv2 (512 tiles), grid logical (8,8,8)
        for (int j = 0; j < 8; ++j) {
            int t = eb * 8 + j;
            gemm_tile(xb1, 131584, 256, 768, wr2, 512, c2b, nullptr, xb2, 132096, 1,
                      t & 7, (t >> 3) & 7, t >> 6, As, Bs);
        }
        stage_signal(&cnts[2]);
        stage_wait(&cnts[2], 64);
        // stage D: conv3 (256 tiles, 4 per block), grid logical (4,8,8)
        for (int j = 0; j < 4; ++j) {
            int t = eb * 4 + j;
            gemm_tile(xb2, 132096, 512, 1536, wr3, 512, c3b, nullptr, enc, 131072, 2,
                      t & 3, (t >> 2) & 7, t >> 5, As, Bs);
        }
        stage_signal(&cnts[3]);
        stage_wait(&cnts[3], 64);
        // stage E: collapsed attention, blocks 0..7 (one per batch)
        if (eb < 8) {
            float* aw = As;           // 512
            float* pr = As + 512;     // 256
            float* red = As + 768;    // 8
            const int b = eb;
            if (tid < 128) ((float4*)aw)[tid] = ((const float4*)(attn_w + 512))[tid];
            __syncthreads();
            const float* er = enc + (size_t)(b * 256 + tid) * 512;
            float4 a4 = make_float4(0, 0, 0, 0);
#pragma unroll 8
            for (int i = 0; i < 128; ++i) {
                float4 e4 = *(const float4*)(er + i * 4);
                float4 w4 = *(const float4*)(aw + i * 4);
                fma4(a4, e4, w4);
            }
            float v = hsum4(a4);
            float m = v;
#pragma unroll
            for (int off = 32; off > 0; off >>= 1) m = fmaxf(m, __shfl_xor(m, off));
            if ((tid & 63) == 0) red[tid >> 6] = m;
            __syncthreads();
            if (tid == 0) red[4] = fmaxf(fmaxf(red[0], red[1]), fmaxf(red[2], red[3]));
            __syncthreads();
            float e = expf(v - red[4]);
            pr[tid] = e;
            float sum = e;
#pragma unroll
            for (int off = 32; off > 0; off >>= 1) sum += __shfl_xor(sum, off);
            if ((tid & 63) == 0) red[tid >> 6] = sum;
            __syncthreads();
            if (tid == 0) red[5] = red[0] + red[1] + red[2] + red[3];
            __syncthreads();
            float inv = 1.f / red[5];
            for (int hh = tid; hh < 512; hh += 256) {
                float acc2 = 0.f;
#pragma unroll 8
                for (int s2 = 0; s2 < 256; ++s2)
                    acc2 = fmaf(pr[s2], enc[(size_t)(b * 256 + s2) * 512 + hh], acc2);
                ctx[b * 512 + hh] = acc2 * inv;
            }
            stage_signal(&cnts[4]);
        }
        stage_wait(&cnts[4], 8);
        // stage F: broadcast ctx -> out[20480 ..] (262144 f4 over 64 blocks)
        float* outc = outp + 20480;
        for (int fi = gidx; fi < 262144; fi += 16384) {
            int h4 = fi & 127;
            int b = fi >> 15;
            ((float4*)outc)[fi] = ((const float4*)(ctx))[b * 128 + h4];
        }
    }
}

// ---------------- output head ----------------
__launch_bounds__(256)
__global__ void out_proj_kernel(const float* __restrict__ h1s, const float* __restrict__ ow,
                                const float* __restrict__ ob, float* __restrict__ out) {
    int lane = threadIdx.x & 63;
    int m = blockIdx.x * 4 + (threadIdx.x >> 6);    // 0..2047, m = t*8+b
    int t = m >> 3, b = m & 7;
    const float* dr = h1s + (size_t)(t + 1) * 4096 + b * 512 + lane * 8;
    float4 d0 = *(const float4*)dr;
    float4 d1 = *(const float4*)(dr + 4);
    float acc[10];
#pragma unroll
    for (int v = 0; v < 10; ++v) {
        const float* wr = ow + v * 512 + lane * 8;
        float4 w0 = *(const float4*)wr, w1 = *(const float4*)(wr + 4);
        acc[v] = d0.x * w0.x + d0.y * w0.y + d0.z * w0.z + d0.w * w0.w +
                 d1.x * w1.x + d1.y * w1.y + d1.z * w1.z + d1.w * w1.w;
    }
#pragma unroll
    for (int v = 0; v < 10; ++v)
#pragma unroll
        for (int off = 32; off > 0; off >>= 1) acc[v] += __shfl_xor(acc[v], off);
    if (lane == 0) {
        float* o = out + (size_t)(b * 256 + t) * 10;
#pragma unroll
        for (int v = 0; v < 10; ++v) o[v] = acc[v] + ob[v];
    }
}

// ---------------- launch ----------------
extern "C" void kernel_launch(void* const* d_in, const int* in_sizes, int n_in,
                              void* d_out, int out_size, void* d_ws, size_t ws_size,
                              hipStream_t stream) {
    const int* src = (const int*)d_in[0];
    const int* tgt = (const int*)d_in[1];
    const float* emb = (const float*)d_in[2];
    const float* c1w = (const float*)d_in[3];
    const float* c1b = (const float*)d_in[4];
    const float* c2w = (const float*)d_in[5];
    const float* c2b = (const float*)d_in[6];
    const float* c3w = (const float*)d_in[7];
    const float* c3b = (const float*)d_in[8];
    const float* wih0 = (const float*)d_in[9];
    const float* whh0 = (const float*)d_in[10];
    const float* bih0 = (const float*)d_in[11];
    const float* bhh0 = (const float*)d_in[12];
    const float* wih1 = (const float*)d_in[13];
    const float* whh1 = (const float*)d_in[14];
    const float* bih1 = (const float*)d_in[15];
    const float* bhh1 = (const float*)d_in[16];
    const float* attn_w = (const float*)d_in[17];
    const float* out_w = (const float*)d_in[19];
    const float* out_b = (const float*)d_in[20];

    float* ws = (float*)d_ws;
    float* wr0 = ws + OWR0;
    float* etg = ws + OTGT;
    float* xg0 = ws + OXG0;
    float* h0s = ws + OH0S;
    float* h1s = ws + OH1S;
    int* flags = (int*)(ws + OFLG);
    int* cnts = (int*)(ws + OCNT);
    float* outp = (float*)d_out;

    init_kernel<<<1024, 256, 0, stream>>>(ws, flags, cnts);
    gather_tgt_kernel<<<512, 256, 0, stream>>>(tgt, emb, etg);
    tr_mat_kernel<<<2048, 256, 0, stream>>>(wih0, wr0, 2048, 256);
    // xg0 = embtgt @ wih0^T + bih0 + bhh0 (full-GPU, pre-LSTM critical path)
    gemm_kernel<<<dim3(32, 32, 1), 256, 0, stream>>>(etg, 0, 256, 256, wr0, 2048,
                                                     bih0, bhh0, xg0, 0, 0);
    // fused persistent LSTM + encoder pipeline
    lstm_fused_kernel<<<256, 256, 0, stream>>>(xg0, whh0, wih1, whh1, bih1, bhh1,
                                               h0s, h1s, flags, cnts,
                                               src, emb, c1w, c1b, c2w, c2b, c3w, c3b,
                                               attn_w, ws, outp);
    // output logits
    out_proj_kernel<<<512, 256, 0, stream>>>(h1s, out_w, out_b, outp);
}